// Round 1
// 723.530 us; speedup vs baseline: 1.1255x; 1.1255x over previous
//
#include <hip/hip_runtime.h>
#include <hip/hip_fp16.h>

typedef float    f32x4 __attribute__((ext_vector_type(4)));
typedef _Float16 f16x8 __attribute__((ext_vector_type(8)));

__device__ __forceinline__ float sigmoidf_(float x) { return __builtin_amdgcn_rcpf(1.f + __expf(-x)); }
__device__ __forceinline__ float tanhf_(float x) { float e = __expf(2.f * x); return 1.f - 2.f * __builtin_amdgcn_rcpf(e + 1.f); }
__device__ __forceinline__ float lrelu_(float v) { return v > 0.f ? v : 0.01f * v; }

__device__ __forceinline__ f16x8 cvt8(const float* p) {
    const f32x4* q = (const f32x4*)p;
    f32x4 a = q[0], b = q[1];
    f16x8 v;
    v[0] = (_Float16)a[0]; v[1] = (_Float16)a[1]; v[2] = (_Float16)a[2]; v[3] = (_Float16)a[3];
    v[4] = (_Float16)b[0]; v[5] = (_Float16)b[1]; v[6] = (_Float16)b[2]; v[7] = (_Float16)b[3];
    return v;
}

__device__ __forceinline__ void gload_lds16(const void* g, void* l) {
    __builtin_amdgcn_global_load_lds(
        (const __attribute__((address_space(1))) void*)g,
        (__attribute__((address_space(3))) void*)l,
        16, 0, 0);
}

// ---------------- LayerNorm + cast to f16, TIME-MAJOR [T][N][128] ----------------
__global__ __launch_bounds__(256) void k_ln(const float* __restrict__ x,
                                            const float* __restrict__ g,
                                            const float* __restrict__ b,
                                            _Float16* __restrict__ xn, int N)
{
    int tid = threadIdx.x;
    int r = tid >> 4, i = tid & 15;
    size_t row = (size_t)blockIdx.x * 16 + r;          // row = n*64 + t
    int n = (int)(row >> 6), t = (int)(row & 63);
    const f32x4* xp = (const f32x4*)(x + row * 128 + i * 8);
    f32x4 a0 = xp[0], a1 = xp[1];
    float v0=a0[0], v1=a0[1], v2=a0[2], v3=a0[3], v4=a1[0], v5=a1[1], v6=a1[2], v7=a1[3];
    float s  = v0+v1+v2+v3+v4+v5+v6+v7;
    float s2 = v0*v0+v1*v1+v2*v2+v3*v3+v4*v4+v5*v5+v6*v6+v7*v7;
#pragma unroll
    for (int m = 1; m <= 8; m <<= 1) { s += __shfl_xor(s, m); s2 += __shfl_xor(s2, m); }
    float mu  = s * (1.f / 128.f);
    float var = s2 * (1.f / 128.f) - mu * mu;
    float rs  = rsqrtf(var + 1e-5f);
    const f32x4* gp = (const f32x4*)(g + i * 8);
    const f32x4* bp = (const f32x4*)(b + i * 8);
    f32x4 g0 = gp[0], g1 = gp[1], bb0 = bp[0], bb1 = bp[1];
    f16x8 o;
    o[0] = (_Float16)((v0 - mu) * rs * g0[0] + bb0[0]);
    o[1] = (_Float16)((v1 - mu) * rs * g0[1] + bb0[1]);
    o[2] = (_Float16)((v2 - mu) * rs * g0[2] + bb0[2]);
    o[3] = (_Float16)((v3 - mu) * rs * g0[3] + bb0[3]);
    o[4] = (_Float16)((v4 - mu) * rs * g1[0] + bb1[0]);
    o[5] = (_Float16)((v5 - mu) * rs * g1[1] + bb1[1]);
    o[6] = (_Float16)((v6 - mu) * rs * g1[2] + bb1[2]);
    o[7] = (_Float16)((v7 - mu) * rs * g1[3] + bb1[3]);
    *(f16x8*)(xn + ((size_t)t * N + n) * 128 + i * 8) = o;
}

// ---------------- Fused 2-layer GRU ----------------
// One block = 16 sequences, 512 threads = 8 waves, each wave owns 16 units of both
// layers. h1 (layer-0 output) lives only in LDS; the ONLY global traffic in the
// loop is the prefetched time-major x-tile (4 KB, global_load_lds, XOR-swizzled).
__global__ __launch_bounds__(512, 2) void k_gru2(const _Float16* __restrict__ xin,
                                                 const float* __restrict__ W_ih0,
                                                 const float* __restrict__ W_hh0,
                                                 const float* __restrict__ b_ih0,
                                                 const float* __restrict__ b_hh0,
                                                 const float* __restrict__ W_ih1,
                                                 const float* __restrict__ W_hh1,
                                                 const float* __restrict__ b_ih1,
                                                 const float* __restrict__ b_hh1,
                                                 float* __restrict__ es, int N)
{
    __shared__ __align__(16) _Float16 hbuf0[2][16 * 136];
    __shared__ __align__(16) _Float16 hbuf1[2][16 * 136];
    __shared__ __align__(16) _Float16 xls[2][16 * 128];   // linear, XOR-swizzled content

    int tid = threadIdx.x;
    int w = tid >> 6, lane = tid & 63;
    int ul = lane & 15, q = lane >> 4;
    int u = w * 16 + ul;
    int n0 = blockIdx.x * 16;

    f16x8 wih0[12], whh0[12], wih1[12], whh1[12];
#pragma unroll
    for (int g = 0; g < 3; ++g)
#pragma unroll
        for (int kt = 0; kt < 4; ++kt) {
            size_t roff = (size_t)(u + g * 128) * 128 + kt * 32 + q * 8;
            wih0[g * 4 + kt] = cvt8(W_ih0 + roff);
            whh0[g * 4 + kt] = cvt8(W_hh0 + roff);
            wih1[g * 4 + kt] = cvt8(W_ih1 + roff);
            whh1[g * 4 + kt] = cvt8(W_hh1 + roff);
        }
    float br0 = b_ih0[u] + b_hh0[u], bz0 = b_ih0[u + 128] + b_hh0[u + 128];
    float bin0 = b_ih0[u + 256], bhn0 = b_hh0[u + 256];
    float br1 = b_ih1[u] + b_hh1[u], bz1 = b_ih1[u + 128] + b_hh1[u + 128];
    float bin1 = b_ih1[u + 256], bhn1 = b_hh1[u + 256];

    for (int idx = tid; idx < 16 * 136; idx += 512) {
        hbuf0[0][idx] = (_Float16)0.f;
        hbuf1[0][idx] = (_Float16)0.f;
    }
    // prologue: stage x-tile for t=0 into xls[0]
    if (w < 4) {
        const char* gsrc = (const char*)(xin + (size_t)n0 * 128);
        int d = w * 1024 + (lane << 4);
        int sw = ((d >> 8) & 7) << 4;
        gload_lds16(gsrc + (d ^ sw), (void*)((char*)&xls[0][0] + w * 1024));
    }
    float h0j[4] = {0.f, 0.f, 0.f, 0.f}, h1j[4] = {0.f, 0.f, 0.f, 0.f};
    __syncthreads();

    const f32x4 Z4 = {0.f, 0.f, 0.f, 0.f};

#define GSTEP(P, T)                                                                       \
    {                                                                                     \
        if ((T) + 1 < 64 && w < 4) {                                                      \
            const char* gsrc = (const char*)(xin + ((size_t)((T) + 1) * N + n0) * 128);   \
            int d = w * 1024 + (lane << 4);                                               \
            int sw = ((d >> 8) & 7) << 4;                                                 \
            gload_lds16(gsrc + (d ^ sw), (void*)((char*)&xls[(P) ^ 1][0] + w * 1024));    \
        }                                                                                 \
        f32x4 ar = Z4, az = Z4, anx = Z4, anh = Z4;                                       \
        {                                                                                 \
            const char* xb = (const char*)&xls[P][0];                                     \
            const _Float16* hb = &hbuf0[P][ul * 136 + q * 8];                             \
            _Pragma("unroll")                                                             \
            for (int kt = 0; kt < 4; ++kt) {                                              \
                f16x8 xv = *(const f16x8*)(xb +                                           \
                            ((ul * 256 + kt * 64 + q * 16) ^ ((ul & 7) << 4)));           \
                f16x8 hv = *(const f16x8*)(hb + kt * 32);                                 \
                ar  = __builtin_amdgcn_mfma_f32_16x16x32_f16(xv, wih0[kt],      ar, 0,0,0); \
                ar  = __builtin_amdgcn_mfma_f32_16x16x32_f16(hv, whh0[kt],      ar, 0,0,0); \
                az  = __builtin_amdgcn_mfma_f32_16x16x32_f16(xv, wih0[4 + kt],  az, 0,0,0); \
                az  = __builtin_amdgcn_mfma_f32_16x16x32_f16(hv, whh0[4 + kt],  az, 0,0,0); \
                anx = __builtin_amdgcn_mfma_f32_16x16x32_f16(xv, wih0[8 + kt], anx, 0,0,0); \
                anh = __builtin_amdgcn_mfma_f32_16x16x32_f16(hv, whh0[8 + kt], anh, 0,0,0); \
            }                                                                             \
        }                                                                                 \
        _Pragma("unroll")                                                                 \
        for (int j = 0; j < 4; ++j) {                                                     \
            float rr = sigmoidf_(ar[j] + br0);                                            \
            float zz = sigmoidf_(az[j] + bz0);                                            \
            float nn = tanhf_(anx[j] + bin0 + rr * (anh[j] + bhn0));                      \
            float hn = (1.f - zz) * nn + zz * h0j[j];                                     \
            h0j[j] = hn;                                                                  \
            hbuf0[(P) ^ 1][(q * 4 + j) * 136 + u] = (_Float16)hn;                         \
        }                                                                                 \
        __syncthreads();                                                                  \
        ar = Z4; az = Z4; anx = Z4; anh = Z4;                                             \
        {                                                                                 \
            const _Float16* xb1 = &hbuf0[(P) ^ 1][ul * 136 + q * 8];                      \
            const _Float16* hb1 = &hbuf1[P][ul * 136 + q * 8];                            \
            _Pragma("unroll")                                                             \
            for (int kt = 0; kt < 4; ++kt) {                                              \
                f16x8 xv = *(const f16x8*)(xb1 + kt * 32);                                \
                f16x8 hv = *(const f16x8*)(hb1 + kt * 32);                                \
                ar  = __builtin_amdgcn_mfma_f32_16x16x32_f16(xv, wih1[kt],      ar, 0,0,0); \
                ar  = __builtin_amdgcn_mfma_f32_16x16x32_f16(hv, whh1[kt],      ar, 0,0,0); \
                az  = __builtin_amdgcn_mfma_f32_16x16x32_f16(xv, wih1[4 + kt],  az, 0,0,0); \
                az  = __builtin_amdgcn_mfma_f32_16x16x32_f16(hv, whh1[4 + kt],  az, 0,0,0); \
                anx = __builtin_amdgcn_mfma_f32_16x16x32_f16(xv, wih1[8 + kt], anx, 0,0,0); \
                anh = __builtin_amdgcn_mfma_f32_16x16x32_f16(hv, whh1[8 + kt], anh, 0,0,0); \
            }                                                                             \
        }                                                                                 \
        _Pragma("unroll")                                                                 \
        for (int j = 0; j < 4; ++j) {                                                     \
            float rr = sigmoidf_(ar[j] + br1);                                            \
            float zz = sigmoidf_(az[j] + bz1);                                            \
            float nn = tanhf_(anx[j] + bin1 + rr * (anh[j] + bhn1));                      \
            float hn = (1.f - zz) * nn + zz * h1j[j];                                     \
            h1j[j] = hn;                                                                  \
            hbuf1[(P) ^ 1][(q * 4 + j) * 136 + u] = (_Float16)hn;                         \
        }                                                                                 \
        __syncthreads();                                                                  \
    }

    for (int t = 0; t < 64; t += 2) {
        GSTEP(0, t)
        GSTEP(1, t + 1)
    }
#undef GSTEP

#pragma unroll
    for (int j = 0; j < 4; ++j)
        es[(size_t)(n0 + q * 4 + j) * 128 + u] = h1j[j];
}

// ---------------- Generic small matmul ----------------
__global__ __launch_bounds__(256) void k_mm(const float* __restrict__ A,
                                            const float* __restrict__ W,
                                            const float* __restrict__ bias,
                                            float* __restrict__ out,
                                            float* __restrict__ rowsum,
                                            int O, int act)
{
    __shared__ __align__(16) _Float16 Wls[128 * 136];
    int tid = threadIdx.x;
    int total = O * 128;
    for (int idx = tid; idx < total; idx += 256) {
        int o = idx >> 7, k = idx & 127;
        Wls[o * 136 + k] = (_Float16)W[idx];
    }
    __syncthreads();
    int o = tid & (O - 1);
    int r = tid / O;
    int R = 256 / O;
    size_t n = (size_t)blockIdx.x * R + r;
    const f32x4* Ap = (const f32x4*)(A + n * 128);
    float acc = bias ? bias[o] : 0.f;
#pragma unroll 4
    for (int k8 = 0; k8 < 16; ++k8) {
        f16x8 wv = *(const f16x8*)&Wls[o * 136 + k8 * 8];
        f32x4 a0 = Ap[k8 * 2], a1 = Ap[k8 * 2 + 1];
        acc += (float)wv[0] * a0[0] + (float)wv[1] * a0[1] + (float)wv[2] * a0[2] + (float)wv[3] * a0[3]
             + (float)wv[4] * a1[0] + (float)wv[5] * a1[1] + (float)wv[6] * a1[2] + (float)wv[7] * a1[3];
    }
    float v = acc;
    if (act == 1) v = lrelu_(v);
    else if (act == 2) v = sigmoidf_(v);
    out[n * O + o] = v;
    if (rowsum) {
        float s = v;
#pragma unroll
        for (int m = 1; m < 32; m <<= 1) s += __shfl_xor(s, m);
        if (o == 0) rowsum[n] = s;
    }
}

// ---------------- edge reduce, stage 1: blocked outer-product partials ----------------
__global__ __launch_bounds__(256) void k_edge_part(const void* __restrict__ S, int isInt,
                                                   const float* __restrict__ X,
                                                   float* __restrict__ part,
                                                   float* __restrict__ d_e,
                                                   int E, int N, int rowsPerBlk)
{
    int tid = threadIdx.x;
    int pair = tid >> 7, c = tid & 127, lane = tid & 63;
    int JG = E >> 5;
    int jg, rOff, rStep;
    if (JG == 2) { jg = pair; rOff = 0; rStep = 1; }
    else         { jg = 0;    rOff = pair; rStep = 2; }
    int n0 = blockIdx.x * rowsPerBlk;
    int n1 = n0 + rowsPerBlk; if (n1 > N) n1 = N;
    const int* Si = (const int*)S; const float* Sf = (const float*)S;
    int js = jg * 32 + (lane & 31);

    float acc[32];
#pragma unroll
    for (int i = 0; i < 32; ++i) acc[i] = 0.f;
    float dcnt = 0.f;

    for (int n = n0 + rOff; n < n1; n += rStep) {
        float sval = isInt ? (float)Si[(size_t)n * E + js] : Sf[(size_t)n * E + js];
        float xc = X[(size_t)n * 128 + c];
        dcnt += sval;
        int sv = __float_as_int(sval);
#pragma unroll
        for (int jj = 0; jj < 32; ++jj) {
            float s = __int_as_float(__builtin_amdgcn_readlane(sv, jj));
            acc[jj] += s * xc;
        }
    }
    float* pp = part + ((size_t)(blockIdx.x * 2 + pair) * 32) * 128;
#pragma unroll
    for (int jj = 0; jj < 32; ++jj)
        pp[(size_t)jj * 128 + c] = acc[jj];
    int w = tid >> 6;
    if ((w & 1) == 0 && (lane & 32) == 0)
        atomicAdd(&d_e[jg * 32 + lane], dcnt);
}

// ---------------- edge reduce, stage 2: sum partials, scale by 1/d_e ----------------
__global__ __launch_bounds__(128) void k_edge_finish(const float* __restrict__ part,
                                                     const float* __restrict__ d_e,
                                                     float* __restrict__ m, int P, int JG)
{
    int j = blockIdx.x, c = threadIdx.x;
    float acc = 0.f;
    if (JG == 2) {
        int pair = j >> 5, jj = j & 31;
        for (int b = 0; b < P; ++b)
            acc += part[((size_t)(b * 2 + pair) * 32 + jj) * 128 + c];
    } else {
        for (int b = 0; b < 2 * P; ++b)
            acc += part[((size_t)b * 32 + j) * 128 + c];
    }
    float d = d_e[j];
    float s = d > 0.f ? 1.f / d : 0.f;
    m[j * 128 + c] = acc * s;
}

// ---------------- hconv apply ----------------
__global__ __launch_bounds__(256) void k_hconv_apply(const void* __restrict__ S, int isInt, int E,
                                                     const float* __restrict__ m,
                                                     const float* __restrict__ dn_pre, int sqrtMode,
                                                     const float* __restrict__ bias,
                                                     const float* __restrict__ base,
                                                     float* __restrict__ outMain,
                                                     float* __restrict__ outSub)
{
    __shared__ float mls[64 * 128];
    int tid = threadIdx.x;
    for (int idx = tid; idx < E * 128; idx += 256) mls[idx] = m[idx];
    __syncthreads();
    int c = tid & 127, r = tid >> 7;
    size_t n = (size_t)blockIdx.x * 2 + r;
    const int* Si = (const int*)S; const float* Sf = (const float*)S;
    float acc = 0.f, d = 0.f;
    for (int j = 0; j < E; ++j) {
        float s = isInt ? (float)Si[n * E + j] : Sf[n * E + j];
        acc += s * mls[j * 128 + c];
        d += s;
    }
    if (dn_pre) d = dn_pre[n];
    float sc = d > 0.f ? (sqrtMode ? rsqrtf(d) : 1.f / d) : 0.f;
    float v = acc * sc + (bias ? bias[c] : 0.f);
    v = lrelu_(v);
    outMain[n * 128 + c] = v;
    if (outSub) outSub[n * 128 + c] = base[n * 128 + c] - v;
}

// ---------------- final projection ----------------
__global__ __launch_bounds__(256) void k_final(const float* __restrict__ ep,
                                               const float* __restrict__ eh,
                                               const float* __restrict__ ea,
                                               const float* __restrict__ Wf,
                                               const float* __restrict__ bf,
                                               float* __restrict__ out, int N)
{
    int wv = threadIdx.x >> 6, lane = threadIdx.x & 63;
    int n = blockIdx.x * 4 + wv;
    if (n >= N) return;
    size_t base = (size_t)n * 128;
    float acc = ep[base + lane] * Wf[lane]       + ep[base + lane + 64] * Wf[lane + 64]
              + eh[base + lane] * Wf[128 + lane] + eh[base + lane + 64] * Wf[128 + lane + 64]
              + ea[base + lane] * Wf[256 + lane] + ea[base + lane + 64] * Wf[256 + lane + 64];
#pragma unroll
    for (int m2 = 1; m2 < 64; m2 <<= 1) acc += __shfl_xor(acc, m2);
    if (lane == 0) out[n] = acc + bf[0];
}

extern "C" void kernel_launch(void* const* d_in, const int* in_sizes, int n_in,
                              void* d_out, int out_size, void* d_ws, size_t ws_size,
                              hipStream_t stream)
{
    const float* x     = (const float*)d_in[0];
    const int*   Hp    = (const int*)d_in[1];
    const float* ln_g  = (const float*)d_in[2];
    const float* ln_b  = (const float*)d_in[3];
    const float* W_ih0 = (const float*)d_in[4];
    const float* W_hh0 = (const float*)d_in[5];
    const float* b_ih0 = (const float*)d_in[6];
    const float* b_hh0 = (const float*)d_in[7];
    const float* W_ih1 = (const float*)d_in[8];
    const float* W_hh1 = (const float*)d_in[9];
    const float* b_ih1 = (const float*)d_in[10];
    const float* b_hh1 = (const float*)d_in[11];
    const float* Wp    = (const float*)d_in[12];
    const float* bp    = (const float*)d_in[13];
    const float* prot  = (const float*)d_in[14];
    const float* Ws    = (const float*)d_in[15];
    const float* bs    = (const float*)d_in[16];
    const float* Wa    = (const float*)d_in[17];
    const float* ba    = (const float*)d_in[18];
    const float* Wf    = (const float*)d_in[19];
    const float* bf    = (const float*)d_in[20];
    float* out = (float*)d_out;
    (void)n_in; (void)out_size; (void)ws_size;

    const int T = 64, E = 64, K = 32;
    int N = in_sizes[0] / (T * 128);         // 4000
    size_t NT = (size_t)N * T;

    const int ROWS_PER_BLK = 16;
    int P = (N + ROWS_PER_BLK - 1) / ROWS_PER_BLK;   // 250

    char* ws = (char*)d_ws;
    size_t off = 0;
    auto alloc = [&](size_t bytes) { char* p = ws + off; off += (bytes + 255) & ~(size_t)255; return p; };
    _Float16* xn  = (_Float16*)alloc(NT * 128 * 2);
    float* e_s   = (float*)alloc((size_t)N * 128 * 4);
    float* t1    = (float*)alloc((size_t)N * 128 * 4);
    float* e_p   = (float*)alloc((size_t)N * 128 * 4);
    float* e_r   = (float*)alloc((size_t)N * 128 * 4);
    float* beta  = (float*)alloc((size_t)N * K * 4);
    float* dn2   = (float*)alloc((size_t)N * 4);
    float* xW    = (float*)alloc((size_t)N * 128 * 4);
    float* e_h   = (float*)alloc((size_t)N * 128 * 4);
    float* e_res = (float*)alloc((size_t)N * 128 * 4);
    float* e_al  = (float*)alloc((size_t)N * 128 * 4);
    float* part  = (float*)alloc((size_t)P * 2 * 32 * 128 * 4);   // 8 MB partials
    float* macc  = (float*)alloc((64 * 128 + 64 + 32 * 128 + 32) * 4);
    float* m_e  = macc;
    float* d_e  = macc + 64 * 128;
    float* m2   = d_e + 64;
    float* d_e2 = m2 + 32 * 128;

    k_ln<<<(int)(NT / 16), 256, 0, stream>>>(x, ln_g, ln_b, xn, N);
    k_gru2<<<N / 16, 512, 0, stream>>>(xn, W_ih0, W_hh0, b_ih0, b_hh0,
                                       W_ih1, W_hh1, b_ih1, b_hh1, e_s, N);

    hipMemsetAsync(macc, 0, (64 * 128 + 64 + 32 * 128 + 32) * 4, stream);
    k_mm<<<N / 2, 256, 0, stream>>>(e_s, Wp, nullptr, t1, nullptr, 128, 0);
    k_edge_part<<<P, 256, 0, stream>>>(Hp, 1, t1, part, d_e, E, N, ROWS_PER_BLK);
    k_edge_finish<<<E, 128, 0, stream>>>(part, d_e, m_e, P, 2);
    k_hconv_apply<<<N / 2, 256, 0, stream>>>(Hp, 1, E, m_e, nullptr, 0, bp, e_s, e_p, e_r);

    k_mm<<<N / 2, 256, 0, stream>>>(e_r, Ws, bs, xW, nullptr, 128, 0);
    k_mm<<<N / 8, 256, 0, stream>>>(e_r, prot, nullptr, beta, dn2, 32, 2);
    k_edge_part<<<P, 256, 0, stream>>>(beta, 0, xW, part, d_e2, K, N, ROWS_PER_BLK);
    k_edge_finish<<<K, 128, 0, stream>>>(part, d_e2, m2, P, 1);
    k_hconv_apply<<<N / 2, 256, 0, stream>>>(beta, 0, K, m2, dn2, 1, nullptr, e_r, e_h, e_res);

    k_mm<<<N / 2, 256, 0, stream>>>(e_res, Wa, ba, e_al, nullptr, 128, 1);
    k_final<<<(N + 3) / 4, 256, 0, stream>>>(e_p, e_h, e_al, Wf, bf, out, N);
}

// Round 2
// 709.702 us; speedup vs baseline: 1.1474x; 1.0195x over previous
//
#include <hip/hip_runtime.h>
#include <hip/hip_fp16.h>

typedef float    f32x4 __attribute__((ext_vector_type(4)));
typedef _Float16 f16x8 __attribute__((ext_vector_type(8)));

__device__ __forceinline__ float sigmoidf_(float x) { return __builtin_amdgcn_rcpf(1.f + __expf(-x)); }
__device__ __forceinline__ float tanhf_(float x) { float e = __expf(2.f * x); return 1.f - 2.f * __builtin_amdgcn_rcpf(e + 1.f); }
__device__ __forceinline__ float lrelu_(float v) { return v > 0.f ? v : 0.01f * v; }

__device__ __forceinline__ f16x8 cvt8(const float* p) {
    const f32x4* q = (const f32x4*)p;
    f32x4 a = q[0], b = q[1];
    f16x8 v;
    v[0] = (_Float16)a[0]; v[1] = (_Float16)a[1]; v[2] = (_Float16)a[2]; v[3] = (_Float16)a[3];
    v[4] = (_Float16)b[0]; v[5] = (_Float16)b[1]; v[6] = (_Float16)b[2]; v[7] = (_Float16)b[3];
    return v;
}

__device__ __forceinline__ void gload_lds16(const void* g, void* l) {
    __builtin_amdgcn_global_load_lds(
        (const __attribute__((address_space(1))) void*)g,
        (__attribute__((address_space(3))) void*)l,
        16, 0, 0);
}

// ---------------- LayerNorm + cast to f16, TIME-MAJOR [T][N][128] ----------------
__global__ __launch_bounds__(256) void k_ln(const float* __restrict__ x,
                                            const float* __restrict__ g,
                                            const float* __restrict__ b,
                                            _Float16* __restrict__ xn, int N)
{
    int tid = threadIdx.x;
    int r = tid >> 4, i = tid & 15;
    size_t row = (size_t)blockIdx.x * 16 + r;          // row = n*64 + t
    int n = (int)(row >> 6), t = (int)(row & 63);
    const f32x4* xp = (const f32x4*)(x + row * 128 + i * 8);
    f32x4 a0 = xp[0], a1 = xp[1];
    float v0=a0[0], v1=a0[1], v2=a0[2], v3=a0[3], v4=a1[0], v5=a1[1], v6=a1[2], v7=a1[3];
    float s  = v0+v1+v2+v3+v4+v5+v6+v7;
    float s2 = v0*v0+v1*v1+v2*v2+v3*v3+v4*v4+v5*v5+v6*v6+v7*v7;
#pragma unroll
    for (int m = 1; m <= 8; m <<= 1) { s += __shfl_xor(s, m); s2 += __shfl_xor(s2, m); }
    float mu  = s * (1.f / 128.f);
    float var = s2 * (1.f / 128.f) - mu * mu;
    float rs  = rsqrtf(var + 1e-5f);
    const f32x4* gp = (const f32x4*)(g + i * 8);
    const f32x4* bp = (const f32x4*)(b + i * 8);
    f32x4 g0 = gp[0], g1 = gp[1], bb0 = bp[0], bb1 = bp[1];
    f16x8 o;
    o[0] = (_Float16)((v0 - mu) * rs * g0[0] + bb0[0]);
    o[1] = (_Float16)((v1 - mu) * rs * g0[1] + bb0[1]);
    o[2] = (_Float16)((v2 - mu) * rs * g0[2] + bb0[2]);
    o[3] = (_Float16)((v3 - mu) * rs * g0[3] + bb0[3]);
    o[4] = (_Float16)((v4 - mu) * rs * g1[0] + bb1[0]);
    o[5] = (_Float16)((v5 - mu) * rs * g1[1] + bb1[1]);
    o[6] = (_Float16)((v6 - mu) * rs * g1[2] + bb1[2]);
    o[7] = (_Float16)((v7 - mu) * rs * g1[3] + bb1[3]);
    *(f16x8*)(xn + ((size_t)t * N + n) * 128 + i * 8) = o;
}

// ---------------- Fused 2-layer GRU, slot-shifted pipeline ----------------
// Slot s computes layer0(t=s) and layer1(t=s-1). L1's x-input is h0[s-1], which
// was published at the PREVIOUS slot's barrier -> ONE __syncthreads per slot.
// h0[s-1] fragments are shared: L0's h-operand == L1's x-operand (read once).
// W_ih0 lives in LDS (96 KB, fragment-ordered) so register weights = 3 matrices
// (144 regs) and the wave fits the 256-reg budget without spills.
__global__ __launch_bounds__(512, 2) void k_gru2(const _Float16* __restrict__ xin,
                                                 const float* __restrict__ W_ih0,
                                                 const float* __restrict__ W_hh0,
                                                 const float* __restrict__ b_ih0,
                                                 const float* __restrict__ b_hh0,
                                                 const float* __restrict__ W_ih1,
                                                 const float* __restrict__ W_hh1,
                                                 const float* __restrict__ b_ih1,
                                                 const float* __restrict__ b_hh1,
                                                 float* __restrict__ es, int N)
{
    __shared__ __align__(16) _Float16 wlds[96 * 64 * 8];     // 96 KB: W_ih0 fragments
    __shared__ __align__(16) _Float16 hbuf0[2][16 * 136];
    __shared__ __align__(16) _Float16 hbuf1[2][16 * 136];
    __shared__ __align__(16) _Float16 xls[2][16 * 128];      // linear, XOR-swizzled content

    int tid = threadIdx.x;
    int w = tid >> 6, lane = tid & 63;
    int ul = lane & 15, q = lane >> 4;
    int u = w * 16 + ul;
    int n0 = blockIdx.x * 16;

    // stage W_ih0 fragments into LDS (each thread writes its own lane slots)
#pragma unroll
    for (int g = 0; g < 3; ++g)
#pragma unroll
        for (int kt = 0; kt < 4; ++kt) {
            f16x8 v = cvt8(W_ih0 + (size_t)(u + g * 128) * 128 + kt * 32 + q * 8);
            *(f16x8*)&wlds[(size_t)((w * 12 + g * 4 + kt) * 64 + lane) * 8] = v;
        }
    const _Float16* wbase = &wlds[(size_t)(w * 12 * 64 + lane) * 8];

    // register weights: W_hh0, W_ih1, W_hh1
    f16x8 whh0[12], wih1[12], whh1[12];
#pragma unroll
    for (int g = 0; g < 3; ++g)
#pragma unroll
        for (int kt = 0; kt < 4; ++kt) {
            size_t roff = (size_t)(u + g * 128) * 128 + kt * 32 + q * 8;
            whh0[g * 4 + kt] = cvt8(W_hh0 + roff);
            wih1[g * 4 + kt] = cvt8(W_ih1 + roff);
            whh1[g * 4 + kt] = cvt8(W_hh1 + roff);
        }
    float br0 = b_ih0[u] + b_hh0[u], bz0 = b_ih0[u + 128] + b_hh0[u + 128];
    float bin0 = b_ih0[u + 256], bhn0 = b_hh0[u + 256];
    float br1 = b_ih1[u] + b_hh1[u], bz1 = b_ih1[u + 128] + b_hh1[u + 128];
    float bin1 = b_ih1[u + 256], bhn1 = b_hh1[u + 256];

    for (int idx = tid; idx < 16 * 136; idx += 512) {
        hbuf0[0][idx] = (_Float16)0.f;
        hbuf1[0][idx] = (_Float16)0.f;
        hbuf1[1][idx] = (_Float16)0.f;
    }
    float h0j[4] = {0.f, 0.f, 0.f, 0.f}, h1j[4] = {0.f, 0.f, 0.f, 0.f};
    const f32x4 Z4 = {0.f, 0.f, 0.f, 0.f};

#define PREF_X(T, PB)                                                                \
    if (w < 4) {                                                                     \
        const char* gsrc = (const char*)(xin + ((size_t)(T) * N + n0) * 128);        \
        int d = w * 1024 + (lane << 4);                                              \
        int sw = ((d >> 8) & 7) << 4;                                                \
        gload_lds16(gsrc + (d ^ sw), (void*)((char*)&xls[PB][0] + w * 1024));        \
    }

#define LOAD_XF(XF, PB)                                                              \
    { const char* xb = (const char*)&xls[PB][0];                                     \
      _Pragma("unroll")                                                              \
      for (int kt = 0; kt < 4; ++kt)                                                 \
          XF[kt] = *(const f16x8*)(xb + ((ul * 256 + kt * 64 + q * 16) ^ ((ul & 7) << 4))); }

#define LOAD_HF(HF, BUF, PB)                                                         \
    { const _Float16* hb = &BUF[PB][ul * 136 + q * 8];                               \
      _Pragma("unroll")                                                              \
      for (int kt = 0; kt < 4; ++kt) HF[kt] = *(const f16x8*)(hb + kt * 32); }

#define L0_COMPUTE(XF, H0F, PW)                                                      \
    { f32x4 ar = Z4, az = Z4, anx = Z4, anh = Z4;                                    \
      _Pragma("unroll")                                                              \
      for (int kt = 0; kt < 4; ++kt) {                                               \
          f16x8 wr = *(const f16x8*)(wbase + (size_t)(kt) * 512);                    \
          f16x8 wz = *(const f16x8*)(wbase + (size_t)(4 + kt) * 512);                \
          f16x8 wn = *(const f16x8*)(wbase + (size_t)(8 + kt) * 512);                \
          ar  = __builtin_amdgcn_mfma_f32_16x16x32_f16(XF[kt], wr, ar, 0, 0, 0);     \
          ar  = __builtin_amdgcn_mfma_f32_16x16x32_f16(H0F[kt], whh0[kt], ar, 0, 0, 0); \
          az  = __builtin_amdgcn_mfma_f32_16x16x32_f16(XF[kt], wz, az, 0, 0, 0);     \
          az  = __builtin_amdgcn_mfma_f32_16x16x32_f16(H0F[kt], whh0[4 + kt], az, 0, 0, 0); \
          anx = __builtin_amdgcn_mfma_f32_16x16x32_f16(XF[kt], wn, anx, 0, 0, 0);    \
          anh = __builtin_amdgcn_mfma_f32_16x16x32_f16(H0F[kt], whh0[8 + kt], anh, 0, 0, 0); \
      }                                                                              \
      _Float16* wb = &hbuf0[PW][0];                                                  \
      _Pragma("unroll")                                                              \
      for (int j = 0; j < 4; ++j) {                                                  \
          float rr = sigmoidf_(ar[j] + br0);                                         \
          float zz = sigmoidf_(az[j] + bz0);                                         \
          float nn = tanhf_(anx[j] + bin0 + rr * (anh[j] + bhn0));                   \
          float hn = (1.f - zz) * nn + zz * h0j[j];                                  \
          h0j[j] = hn;                                                               \
          wb[(q * 4 + j) * 136 + u] = (_Float16)hn;                                  \
      } }

#define L1_MFMA(H0F, H1F)                                                            \
      f32x4 ar = Z4, az = Z4, anx = Z4, anh = Z4;                                    \
      _Pragma("unroll")                                                              \
      for (int kt = 0; kt < 4; ++kt) {                                               \
          ar  = __builtin_amdgcn_mfma_f32_16x16x32_f16(H0F[kt], wih1[kt], ar, 0, 0, 0); \
          ar  = __builtin_amdgcn_mfma_f32_16x16x32_f16(H1F[kt], whh1[kt], ar, 0, 0, 0); \
          az  = __builtin_amdgcn_mfma_f32_16x16x32_f16(H0F[kt], wih1[4 + kt], az, 0, 0, 0); \
          az  = __builtin_amdgcn_mfma_f32_16x16x32_f16(H1F[kt], whh1[4 + kt], az, 0, 0, 0); \
          anx = __builtin_amdgcn_mfma_f32_16x16x32_f16(H0F[kt], wih1[8 + kt], anx, 0, 0, 0); \
          anh = __builtin_amdgcn_mfma_f32_16x16x32_f16(H1F[kt], whh1[8 + kt], anh, 0, 0, 0); \
      }

    // prologue: stage x(0)
    PREF_X(0, 0);
    __syncthreads();

    // slot 0: L0(t=0) only
    {
        PREF_X(1, 1);
        f16x8 xf[4], h0f[4];
        LOAD_XF(xf, 0);
        LOAD_HF(h0f, hbuf0, 0);
        L0_COMPUTE(xf, h0f, 1);
        __syncthreads();
    }

    // slots 1..63: L0(t=s) + L1(t=s-1)
    for (int s = 1; s < 64; ++s) {
        int P = s & 1;
        if (s < 63) { PREF_X(s + 1, P ^ 1); }
        f16x8 xf[4], h0f[4];
        LOAD_XF(xf, P);
        LOAD_HF(h0f, hbuf0, P);          // h0[s-1]: L0 h-operand AND L1 x-operand
        L0_COMPUTE(xf, h0f, P ^ 1);
        {
            f16x8 h1f[4];
            LOAD_HF(h1f, hbuf1, P);
            L1_MFMA(h0f, h1f);
            _Float16* wb = &hbuf1[P ^ 1][0];
#pragma unroll
            for (int j = 0; j < 4; ++j) {
                float rr = sigmoidf_(ar[j] + br1);
                float zz = sigmoidf_(az[j] + bz1);
                float nn = tanhf_(anx[j] + bin1 + rr * (anh[j] + bhn1));
                float hn = (1.f - zz) * nn + zz * h1j[j];
                h1j[j] = hn;
                wb[(q * 4 + j) * 136 + u] = (_Float16)hn;
            }
        }
        __syncthreads();
    }

    // slot 64: L1(t=63) only (no LDS write needed)
    {
        f16x8 h0f[4], h1f[4];
        LOAD_HF(h0f, hbuf0, 0);          // h0[63], written by slot 63 (P=1 -> buf 0)
        LOAD_HF(h1f, hbuf1, 0);          // h1[62]
        L1_MFMA(h0f, h1f);
#pragma unroll
        for (int j = 0; j < 4; ++j) {
            float rr = sigmoidf_(ar[j] + br1);
            float zz = sigmoidf_(az[j] + bz1);
            float nn = tanhf_(anx[j] + bin1 + rr * (anh[j] + bhn1));
            h1j[j] = (1.f - zz) * nn + zz * h1j[j];
        }
    }

#pragma unroll
    for (int j = 0; j < 4; ++j)
        es[(size_t)(n0 + q * 4 + j) * 128 + u] = h1j[j];

#undef PREF_X
#undef LOAD_XF
#undef LOAD_HF
#undef L0_COMPUTE
#undef L1_MFMA
}

// ---------------- Generic small matmul ----------------
__global__ __launch_bounds__(256) void k_mm(const float* __restrict__ A,
                                            const float* __restrict__ W,
                                            const float* __restrict__ bias,
                                            float* __restrict__ out,
                                            float* __restrict__ rowsum,
                                            int O, int act)
{
    __shared__ __align__(16) _Float16 Wls[128 * 136];
    int tid = threadIdx.x;
    int total = O * 128;
    for (int idx = tid; idx < total; idx += 256) {
        int o = idx >> 7, k = idx & 127;
        Wls[o * 136 + k] = (_Float16)W[idx];
    }
    __syncthreads();
    int o = tid & (O - 1);
    int r = tid / O;
    int R = 256 / O;
    size_t n = (size_t)blockIdx.x * R + r;
    const f32x4* Ap = (const f32x4*)(A + n * 128);
    float acc = bias ? bias[o] : 0.f;
#pragma unroll 4
    for (int k8 = 0; k8 < 16; ++k8) {
        f16x8 wv = *(const f16x8*)&Wls[o * 136 + k8 * 8];
        f32x4 a0 = Ap[k8 * 2], a1 = Ap[k8 * 2 + 1];
        acc += (float)wv[0] * a0[0] + (float)wv[1] * a0[1] + (float)wv[2] * a0[2] + (float)wv[3] * a0[3]
             + (float)wv[4] * a1[0] + (float)wv[5] * a1[1] + (float)wv[6] * a1[2] + (float)wv[7] * a1[3];
    }
    float v = acc;
    if (act == 1) v = lrelu_(v);
    else if (act == 2) v = sigmoidf_(v);
    out[n * O + o] = v;
    if (rowsum) {
        float s = v;
#pragma unroll
        for (int m = 1; m < 32; m <<= 1) s += __shfl_xor(s, m);
        if (o == 0) rowsum[n] = s;
    }
}

// ---------------- edge reduce, stage 1: blocked outer-product partials ----------------
__global__ __launch_bounds__(256) void k_edge_part(const void* __restrict__ S, int isInt,
                                                   const float* __restrict__ X,
                                                   float* __restrict__ part,
                                                   float* __restrict__ d_e,
                                                   int E, int N, int rowsPerBlk)
{
    int tid = threadIdx.x;
    int pair = tid >> 7, c = tid & 127, lane = tid & 63;
    int JG = E >> 5;
    int jg, rOff, rStep;
    if (JG == 2) { jg = pair; rOff = 0; rStep = 1; }
    else         { jg = 0;    rOff = pair; rStep = 2; }
    int n0 = blockIdx.x * rowsPerBlk;
    int n1 = n0 + rowsPerBlk; if (n1 > N) n1 = N;
    const int* Si = (const int*)S; const float* Sf = (const float*)S;
    int js = jg * 32 + (lane & 31);

    float acc[32];
#pragma unroll
    for (int i = 0; i < 32; ++i) acc[i] = 0.f;
    float dcnt = 0.f;

    for (int n = n0 + rOff; n < n1; n += rStep) {
        float sval = isInt ? (float)Si[(size_t)n * E + js] : Sf[(size_t)n * E + js];
        float xc = X[(size_t)n * 128 + c];
        dcnt += sval;
        int sv = __float_as_int(sval);
#pragma unroll
        for (int jj = 0; jj < 32; ++jj) {
            float s = __int_as_float(__builtin_amdgcn_readlane(sv, jj));
            acc[jj] += s * xc;
        }
    }
    float* pp = part + ((size_t)(blockIdx.x * 2 + pair) * 32) * 128;
#pragma unroll
    for (int jj = 0; jj < 32; ++jj)
        pp[(size_t)jj * 128 + c] = acc[jj];
    int w = tid >> 6;
    if ((w & 1) == 0 && (lane & 32) == 0)
        atomicAdd(&d_e[jg * 32 + lane], dcnt);
}

// ---------------- edge reduce, stage 2: sum partials, scale by 1/d_e ----------------
__global__ __launch_bounds__(128) void k_edge_finish(const float* __restrict__ part,
                                                     const float* __restrict__ d_e,
                                                     float* __restrict__ m, int P, int JG)
{
    int j = blockIdx.x, c = threadIdx.x;
    float acc = 0.f;
    if (JG == 2) {
        int pair = j >> 5, jj = j & 31;
        for (int b = 0; b < P; ++b)
            acc += part[((size_t)(b * 2 + pair) * 32 + jj) * 128 + c];
    } else {
        for (int b = 0; b < 2 * P; ++b)
            acc += part[((size_t)b * 32 + j) * 128 + c];
    }
    float d = d_e[j];
    float s = d > 0.f ? 1.f / d : 0.f;
    m[j * 128 + c] = acc * s;
}

// ---------------- hconv apply ----------------
__global__ __launch_bounds__(256) void k_hconv_apply(const void* __restrict__ S, int isInt, int E,
                                                     const float* __restrict__ m,
                                                     const float* __restrict__ dn_pre, int sqrtMode,
                                                     const float* __restrict__ bias,
                                                     const float* __restrict__ base,
                                                     float* __restrict__ outMain,
                                                     float* __restrict__ outSub)
{
    __shared__ float mls[64 * 128];
    int tid = threadIdx.x;
    for (int idx = tid; idx < E * 128; idx += 256) mls[idx] = m[idx];
    __syncthreads();
    int c = tid & 127, r = tid >> 7;
    size_t n = (size_t)blockIdx.x * 2 + r;
    const int* Si = (const int*)S; const float* Sf = (const float*)S;
    float acc = 0.f, d = 0.f;
    for (int j = 0; j < E; ++j) {
        float s = isInt ? (float)Si[n * E + j] : Sf[n * E + j];
        acc += s * mls[j * 128 + c];
        d += s;
    }
    if (dn_pre) d = dn_pre[n];
    float sc = d > 0.f ? (sqrtMode ? rsqrtf(d) : 1.f / d) : 0.f;
    float v = acc * sc + (bias ? bias[c] : 0.f);
    v = lrelu_(v);
    outMain[n * 128 + c] = v;
    if (outSub) outSub[n * 128 + c] = base[n * 128 + c] - v;
}

// ---------------- final projection ----------------
__global__ __launch_bounds__(256) void k_final(const float* __restrict__ ep,
                                               const float* __restrict__ eh,
                                               const float* __restrict__ ea,
                                               const float* __restrict__ Wf,
                                               const float* __restrict__ bf,
                                               float* __restrict__ out, int N)
{
    int wv = threadIdx.x >> 6, lane = threadIdx.x & 63;
    int n = blockIdx.x * 4 + wv;
    if (n >= N) return;
    size_t base = (size_t)n * 128;
    float acc = ep[base + lane] * Wf[lane]       + ep[base + lane + 64] * Wf[lane + 64]
              + eh[base + lane] * Wf[128 + lane] + eh[base + lane + 64] * Wf[128 + lane + 64]
              + ea[base + lane] * Wf[256 + lane] + ea[base + lane + 64] * Wf[256 + lane + 64];
#pragma unroll
    for (int m2 = 1; m2 < 64; m2 <<= 1) acc += __shfl_xor(acc, m2);
    if (lane == 0) out[n] = acc + bf[0];
}

extern "C" void kernel_launch(void* const* d_in, const int* in_sizes, int n_in,
                              void* d_out, int out_size, void* d_ws, size_t ws_size,
                              hipStream_t stream)
{
    const float* x     = (const float*)d_in[0];
    const int*   Hp    = (const int*)d_in[1];
    const float* ln_g  = (const float*)d_in[2];
    const float* ln_b  = (const float*)d_in[3];
    const float* W_ih0 = (const float*)d_in[4];
    const float* W_hh0 = (const float*)d_in[5];
    const float* b_ih0 = (const float*)d_in[6];
    const float* b_hh0 = (const float*)d_in[7];
    const float* W_ih1 = (const float*)d_in[8];
    const float* W_hh1 = (const float*)d_in[9];
    const float* b_ih1 = (const float*)d_in[10];
    const float* b_hh1 = (const float*)d_in[11];
    const float* Wp    = (const float*)d_in[12];
    const float* bp    = (const float*)d_in[13];
    const float* prot  = (const float*)d_in[14];
    const float* Ws    = (const float*)d_in[15];
    const float* bs    = (const float*)d_in[16];
    const float* Wa    = (const float*)d_in[17];
    const float* ba    = (const float*)d_in[18];
    const float* Wf    = (const float*)d_in[19];
    const float* bf    = (const float*)d_in[20];
    float* out = (float*)d_out;
    (void)n_in; (void)out_size; (void)ws_size;

    const int T = 64, E = 64, K = 32;
    int N = in_sizes[0] / (T * 128);         // 4000
    size_t NT = (size_t)N * T;

    const int ROWS_PER_BLK = 16;
    int P = (N + ROWS_PER_BLK - 1) / ROWS_PER_BLK;   // 250

    char* ws = (char*)d_ws;
    size_t off = 0;
    auto alloc = [&](size_t bytes) { char* p = ws + off; off += (bytes + 255) & ~(size_t)255; return p; };
    _Float16* xn  = (_Float16*)alloc(NT * 128 * 2);
    float* e_s   = (float*)alloc((size_t)N * 128 * 4);
    float* t1    = (float*)alloc((size_t)N * 128 * 4);
    float* e_p   = (float*)alloc((size_t)N * 128 * 4);
    float* e_r   = (float*)alloc((size_t)N * 128 * 4);
    float* beta  = (float*)alloc((size_t)N * K * 4);
    float* dn2   = (float*)alloc((size_t)N * 4);
    float* xW    = (float*)alloc((size_t)N * 128 * 4);
    float* e_h   = (float*)alloc((size_t)N * 128 * 4);
    float* e_res = (float*)alloc((size_t)N * 128 * 4);
    float* e_al  = (float*)alloc((size_t)N * 128 * 4);
    float* part  = (float*)alloc((size_t)P * 2 * 32 * 128 * 4);   // 8 MB partials
    float* macc  = (float*)alloc((64 * 128 + 64 + 32 * 128 + 32) * 4);
    float* m_e  = macc;
    float* d_e  = macc + 64 * 128;
    float* m2   = d_e + 64;
    float* d_e2 = m2 + 32 * 128;

    k_ln<<<(int)(NT / 16), 256, 0, stream>>>(x, ln_g, ln_b, xn, N);
    k_gru2<<<N / 16, 512, 0, stream>>>(xn, W_ih0, W_hh0, b_ih0, b_hh0,
                                       W_ih1, W_hh1, b_ih1, b_hh1, e_s, N);

    hipMemsetAsync(macc, 0, (64 * 128 + 64 + 32 * 128 + 32) * 4, stream);
    k_mm<<<N / 2, 256, 0, stream>>>(e_s, Wp, nullptr, t1, nullptr, 128, 0);
    k_edge_part<<<P, 256, 0, stream>>>(Hp, 1, t1, part, d_e, E, N, ROWS_PER_BLK);
    k_edge_finish<<<E, 128, 0, stream>>>(part, d_e, m_e, P, 2);
    k_hconv_apply<<<N / 2, 256, 0, stream>>>(Hp, 1, E, m_e, nullptr, 0, bp, e_s, e_p, e_r);

    k_mm<<<N / 2, 256, 0, stream>>>(e_r, Ws, bs, xW, nullptr, 128, 0);
    k_mm<<<N / 8, 256, 0, stream>>>(e_r, prot, nullptr, beta, dn2, 32, 2);
    k_edge_part<<<P, 256, 0, stream>>>(beta, 0, xW, part, d_e2, K, N, ROWS_PER_BLK);
    k_edge_finish<<<K, 128, 0, stream>>>(part, d_e2, m2, P, 1);
    k_hconv_apply<<<N / 2, 256, 0, stream>>>(beta, 0, K, m2, dn2, 1, nullptr, e_r, e_h, e_res);

    k_mm<<<N / 2, 256, 0, stream>>>(e_res, Wa, ba, e_al, nullptr, 128, 1);
    k_final<<<(N + 3) / 4, 256, 0, stream>>>(e_p, e_h, e_al, Wf, bf, out, N);
}

// Round 3
// 673.868 us; speedup vs baseline: 1.2084x; 1.0532x over previous
//
#include <hip/hip_runtime.h>
#include <hip/hip_fp16.h>

typedef float    f32x4 __attribute__((ext_vector_type(4)));
typedef _Float16 f16x8 __attribute__((ext_vector_type(8)));

__device__ __forceinline__ float sigmoidf_(float x) { return __builtin_amdgcn_rcpf(1.f + __expf(-x)); }
__device__ __forceinline__ float tanhf_(float x) { float e = __expf(2.f * x); return 1.f - 2.f * __builtin_amdgcn_rcpf(e + 1.f); }
__device__ __forceinline__ float lrelu_(float v) { return v > 0.f ? v : 0.01f * v; }

__device__ __forceinline__ f16x8 cvt8(const float* p) {
    const f32x4* q = (const f32x4*)p;
    f32x4 a = q[0], b = q[1];
    f16x8 v;
    v[0] = (_Float16)a[0]; v[1] = (_Float16)a[1]; v[2] = (_Float16)a[2]; v[3] = (_Float16)a[3];
    v[4] = (_Float16)b[0]; v[5] = (_Float16)b[1]; v[6] = (_Float16)b[2]; v[7] = (_Float16)b[3];
    return v;
}

__device__ __forceinline__ void gload_lds16(const void* g, void* l) {
    __builtin_amdgcn_global_load_lds(
        (const __attribute__((address_space(1))) void*)g,
        (__attribute__((address_space(3))) void*)l,
        16, 0, 0);
}

// ---------------- LayerNorm + cast to f16, TIME-MAJOR [T][N][128] ----------------
__global__ __launch_bounds__(256) void k_ln(const float* __restrict__ x,
                                            const float* __restrict__ g,
                                            const float* __restrict__ b,
                                            _Float16* __restrict__ xn, int N)
{
    int tid = threadIdx.x;
    int r = tid >> 4, i = tid & 15;
    size_t row = (size_t)blockIdx.x * 16 + r;          // row = n*64 + t
    int n = (int)(row >> 6), t = (int)(row & 63);
    const f32x4* xp = (const f32x4*)(x + row * 128 + i * 8);
    f32x4 a0 = xp[0], a1 = xp[1];
    float v0=a0[0], v1=a0[1], v2=a0[2], v3=a0[3], v4=a1[0], v5=a1[1], v6=a1[2], v7=a1[3];
    float s  = v0+v1+v2+v3+v4+v5+v6+v7;
    float s2 = v0*v0+v1*v1+v2*v2+v3*v3+v4*v4+v5*v5+v6*v6+v7*v7;
#pragma unroll
    for (int m = 1; m <= 8; m <<= 1) { s += __shfl_xor(s, m); s2 += __shfl_xor(s2, m); }
    float mu  = s * (1.f / 128.f);
    float var = s2 * (1.f / 128.f) - mu * mu;
    float rs  = rsqrtf(var + 1e-5f);
    const f32x4* gp = (const f32x4*)(g + i * 8);
    const f32x4* bp = (const f32x4*)(b + i * 8);
    f32x4 g0 = gp[0], g1 = gp[1], bb0 = bp[0], bb1 = bp[1];
    f16x8 o;
    o[0] = (_Float16)((v0 - mu) * rs * g0[0] + bb0[0]);
    o[1] = (_Float16)((v1 - mu) * rs * g0[1] + bb0[1]);
    o[2] = (_Float16)((v2 - mu) * rs * g0[2] + bb0[2]);
    o[3] = (_Float16)((v3 - mu) * rs * g0[3] + bb0[3]);
    o[4] = (_Float16)((v4 - mu) * rs * g1[0] + bb1[0]);
    o[5] = (_Float16)((v5 - mu) * rs * g1[1] + bb1[1]);
    o[6] = (_Float16)((v6 - mu) * rs * g1[2] + bb1[2]);
    o[7] = (_Float16)((v7 - mu) * rs * g1[3] + bb1[3]);
    *(f16x8*)(xn + ((size_t)t * N + n) * 128 + i * 8) = o;
}

// ---------------- Fused 2-layer GRU, slot-shifted pipeline ----------------
// Slot s computes layer0(t=s) and layer1(t=s-1); one __syncthreads per slot.
// W_ih0 in LDS (96 KB); W_hh0/W_ih1/W_hh1 in registers (144 VGPR).
// launch_bounds(512, 1): LDS (121 KB) already limits to 1 block/CU, so the
// 8-wave block forces 2 waves/SIMD -> 256-VGPR budget. (512,2) clamped the
// allocator to 128 VGPR and caused a ~34 MB scratch-spill storm (r2 WRITE_SIZE).
__global__ __launch_bounds__(512, 1) void k_gru2(const _Float16* __restrict__ xin,
                                                 const float* __restrict__ W_ih0,
                                                 const float* __restrict__ W_hh0,
                                                 const float* __restrict__ b_ih0,
                                                 const float* __restrict__ b_hh0,
                                                 const float* __restrict__ W_ih1,
                                                 const float* __restrict__ W_hh1,
                                                 const float* __restrict__ b_ih1,
                                                 const float* __restrict__ b_hh1,
                                                 float* __restrict__ es, int N)
{
    __shared__ __align__(16) _Float16 wlds[96 * 64 * 8];     // 96 KB: W_ih0 fragments
    __shared__ __align__(16) _Float16 hbuf0[2][16 * 136];
    __shared__ __align__(16) _Float16 hbuf1[2][16 * 136];
    __shared__ __align__(16) _Float16 xls[2][16 * 128];      // linear, XOR-swizzled content

    int tid = threadIdx.x;
    int w = tid >> 6, lane = tid & 63;
    int ul = lane & 15, q = lane >> 4;
    int u = w * 16 + ul;
    int n0 = blockIdx.x * 16;

    // stage W_ih0 fragments into LDS (each thread writes its own lane slots)
#pragma unroll
    for (int g = 0; g < 3; ++g)
#pragma unroll
        for (int kt = 0; kt < 4; ++kt) {
            f16x8 v = cvt8(W_ih0 + (size_t)(u + g * 128) * 128 + kt * 32 + q * 8);
            *(f16x8*)&wlds[(size_t)((w * 12 + g * 4 + kt) * 64 + lane) * 8] = v;
        }
    const _Float16* wbase = &wlds[(size_t)(w * 12 * 64 + lane) * 8];

    // register weights: W_hh0, W_ih1, W_hh1
    f16x8 whh0[12], wih1[12], whh1[12];
#pragma unroll
    for (int g = 0; g < 3; ++g)
#pragma unroll
        for (int kt = 0; kt < 4; ++kt) {
            size_t roff = (size_t)(u + g * 128) * 128 + kt * 32 + q * 8;
            whh0[g * 4 + kt] = cvt8(W_hh0 + roff);
            wih1[g * 4 + kt] = cvt8(W_ih1 + roff);
            whh1[g * 4 + kt] = cvt8(W_hh1 + roff);
        }
    float br0 = b_ih0[u] + b_hh0[u], bz0 = b_ih0[u + 128] + b_hh0[u + 128];
    float bin0 = b_ih0[u + 256], bhn0 = b_hh0[u + 256];
    float br1 = b_ih1[u] + b_hh1[u], bz1 = b_ih1[u + 128] + b_hh1[u + 128];
    float bin1 = b_ih1[u + 256], bhn1 = b_hh1[u + 256];

    for (int idx = tid; idx < 16 * 136; idx += 512) {
        hbuf0[0][idx] = (_Float16)0.f;
        hbuf1[0][idx] = (_Float16)0.f;
        hbuf1[1][idx] = (_Float16)0.f;
    }
    float h0j[4] = {0.f, 0.f, 0.f, 0.f}, h1j[4] = {0.f, 0.f, 0.f, 0.f};
    const f32x4 Z4 = {0.f, 0.f, 0.f, 0.f};

    // precomputed addressing
    int xoff[4];
#pragma unroll
    for (int kt = 0; kt < 4; ++kt)
        xoff[kt] = (ul * 256 + kt * 64 + q * 16) ^ ((ul & 7) << 4);
    int dlin = w * 1024 + (lane << 4);
    int dsrc = dlin ^ (((dlin >> 8) & 7) << 4);

#define PREF_X(T, PB)                                                                \
    if (w < 4) {                                                                     \
        const char* gsrc = (const char*)(xin + ((size_t)(T) * N + n0) * 128);        \
        gload_lds16(gsrc + dsrc, (void*)((char*)&xls[PB][0] + dlin));                \
    }

#define LOAD_XF(XF, PB)                                                              \
    { const char* xb = (const char*)&xls[PB][0];                                     \
      _Pragma("unroll")                                                              \
      for (int kt = 0; kt < 4; ++kt)                                                 \
          XF[kt] = *(const f16x8*)(xb + xoff[kt]); }

#define LOAD_HF(HF, BUF, PB)                                                         \
    { const _Float16* hb = &BUF[PB][ul * 136 + q * 8];                               \
      _Pragma("unroll")                                                              \
      for (int kt = 0; kt < 4; ++kt) HF[kt] = *(const f16x8*)(hb + kt * 32); }

#define L0_COMPUTE(XF, H0F, PW)                                                      \
    { f32x4 ar = Z4, az = Z4, anx = Z4, anh = Z4;                                    \
      _Pragma("unroll")                                                              \
      for (int kt = 0; kt < 4; ++kt) {                                               \
          f16x8 wr = *(const f16x8*)(wbase + (size_t)(kt) * 512);                    \
          f16x8 wz = *(const f16x8*)(wbase + (size_t)(4 + kt) * 512);                \
          f16x8 wn = *(const f16x8*)(wbase + (size_t)(8 + kt) * 512);                \
          ar  = __builtin_amdgcn_mfma_f32_16x16x32_f16(XF[kt], wr, ar, 0, 0, 0);     \
          ar  = __builtin_amdgcn_mfma_f32_16x16x32_f16(H0F[kt], whh0[kt], ar, 0, 0, 0); \
          az  = __builtin_amdgcn_mfma_f32_16x16x32_f16(XF[kt], wz, az, 0, 0, 0);     \
          az  = __builtin_amdgcn_mfma_f32_16x16x32_f16(H0F[kt], whh0[4 + kt], az, 0, 0, 0); \
          anx = __builtin_amdgcn_mfma_f32_16x16x32_f16(XF[kt], wn, anx, 0, 0, 0);    \
          anh = __builtin_amdgcn_mfma_f32_16x16x32_f16(H0F[kt], whh0[8 + kt], anh, 0, 0, 0); \
      }                                                                              \
      _Float16* wb = &hbuf0[PW][0];                                                  \
      _Pragma("unroll")                                                              \
      for (int j = 0; j < 4; ++j) {                                                  \
          float rr = sigmoidf_(ar[j] + br0);                                         \
          float zz = sigmoidf_(az[j] + bz0);                                         \
          float nn = tanhf_(anx[j] + bin0 + rr * (anh[j] + bhn0));                   \
          float hn = (1.f - zz) * nn + zz * h0j[j];                                  \
          h0j[j] = hn;                                                               \
          wb[(q * 4 + j) * 136 + u] = (_Float16)hn;                                  \
      } }

#define L1_MFMA(H0F, H1F)                                                            \
      f32x4 ar = Z4, az = Z4, anx = Z4, anh = Z4;                                    \
      _Pragma("unroll")                                                              \
      for (int kt = 0; kt < 4; ++kt) {                                               \
          ar  = __builtin_amdgcn_mfma_f32_16x16x32_f16(H0F[kt], wih1[kt], ar, 0, 0, 0); \
          ar  = __builtin_amdgcn_mfma_f32_16x16x32_f16(H1F[kt], whh1[kt], ar, 0, 0, 0); \
          az  = __builtin_amdgcn_mfma_f32_16x16x32_f16(H0F[kt], wih1[4 + kt], az, 0, 0, 0); \
          az  = __builtin_amdgcn_mfma_f32_16x16x32_f16(H1F[kt], whh1[4 + kt], az, 0, 0, 0); \
          anx = __builtin_amdgcn_mfma_f32_16x16x32_f16(H0F[kt], wih1[8 + kt], anx, 0, 0, 0); \
          anh = __builtin_amdgcn_mfma_f32_16x16x32_f16(H1F[kt], whh1[8 + kt], anh, 0, 0, 0); \
      }

    // prologue: stage x(0)
    PREF_X(0, 0);
    __syncthreads();

    // slot 0: L0(t=0) only
    {
        PREF_X(1, 1);
        f16x8 xf[4], h0f[4];
        LOAD_XF(xf, 0);
        LOAD_HF(h0f, hbuf0, 0);
        L0_COMPUTE(xf, h0f, 1);
        __syncthreads();
    }

    // slots 1..63: L0(t=s) + L1(t=s-1)
    for (int s = 1; s < 64; ++s) {
        int P = s & 1;
        if (s < 63) { PREF_X(s + 1, P ^ 1); }
        f16x8 xf[4], h0f[4];
        LOAD_XF(xf, P);
        LOAD_HF(h0f, hbuf0, P);          // h0[s-1]: L0 h-operand AND L1 x-operand
        L0_COMPUTE(xf, h0f, P ^ 1);
        {
            f16x8 h1f[4];
            LOAD_HF(h1f, hbuf1, P);
            L1_MFMA(h0f, h1f);
            _Float16* wb = &hbuf1[P ^ 1][0];
#pragma unroll
            for (int j = 0; j < 4; ++j) {
                float rr = sigmoidf_(ar[j] + br1);
                float zz = sigmoidf_(az[j] + bz1);
                float nn = tanhf_(anx[j] + bin1 + rr * (anh[j] + bhn1));
                float hn = (1.f - zz) * nn + zz * h1j[j];
                h1j[j] = hn;
                wb[(q * 4 + j) * 136 + u] = (_Float16)hn;
            }
        }
        __syncthreads();
    }

    // slot 64: L1(t=63) only (no LDS write needed)
    {
        f16x8 h0f[4], h1f[4];
        LOAD_HF(h0f, hbuf0, 0);          // h0[63], written by slot 63 (P=1 -> buf 0)
        LOAD_HF(h1f, hbuf1, 0);          // h1[62]
        L1_MFMA(h0f, h1f);
#pragma unroll
        for (int j = 0; j < 4; ++j) {
            float rr = sigmoidf_(ar[j] + br1);
            float zz = sigmoidf_(az[j] + bz1);
            float nn = tanhf_(anx[j] + bin1 + rr * (anh[j] + bhn1));
            h1j[j] = (1.f - zz) * nn + zz * h1j[j];
        }
    }

#pragma unroll
    for (int j = 0; j < 4; ++j)
        es[(size_t)(n0 + q * 4 + j) * 128 + u] = h1j[j];

#undef PREF_X
#undef LOAD_XF
#undef LOAD_HF
#undef L0_COMPUTE
#undef L1_MFMA
}

// ---------------- MFMA 128x128 matmul: out[n][o] = act(A[n,:]·W[o,:] + bias) ----------------
// Same fragment/output mapping as the GRU kernel (verified there). One block =
// 16 rows x 128 outs, 8 waves each own 16 outs. No LDS, no barrier.
__global__ __launch_bounds__(512) void k_mm128(const float* __restrict__ A,
                                               const float* __restrict__ W,
                                               const float* __restrict__ bias,
                                               float* __restrict__ out, int act)
{
    int tid = threadIdx.x;
    int w = tid >> 6, lane = tid & 63;
    int ul = lane & 15, q = lane >> 4;
    int u = w * 16 + ul;
    int n0 = blockIdx.x * 16;

    f32x4 acc = {0.f, 0.f, 0.f, 0.f};
#pragma unroll
    for (int kt = 0; kt < 4; ++kt) {
        f16x8 af = cvt8(A + (size_t)(n0 + ul) * 128 + kt * 32 + q * 8);
        f16x8 wf = cvt8(W + (size_t)u * 128 + kt * 32 + q * 8);
        acc = __builtin_amdgcn_mfma_f32_16x16x32_f16(af, wf, acc, 0, 0, 0);
    }
    float bv = bias ? bias[u] : 0.f;
#pragma unroll
    for (int j = 0; j < 4; ++j) {
        float v = acc[j] + bv;
        if (act == 1) v = lrelu_(v);
        out[(size_t)(n0 + q * 4 + j) * 128 + u] = v;
    }
}

// ---------------- Generic small matmul (O=32 path: beta + rowsum) ----------------
__global__ __launch_bounds__(256) void k_mm(const float* __restrict__ A,
                                            const float* __restrict__ W,
                                            const float* __restrict__ bias,
                                            float* __restrict__ out,
                                            float* __restrict__ rowsum,
                                            int O, int act)
{
    __shared__ __align__(16) _Float16 Wls[128 * 136];
    int tid = threadIdx.x;
    int total = O * 128;
    for (int idx = tid; idx < total; idx += 256) {
        int o = idx >> 7, k = idx & 127;
        Wls[o * 136 + k] = (_Float16)W[idx];
    }
    __syncthreads();
    int o = tid & (O - 1);
    int r = tid / O;
    int R = 256 / O;
    size_t n = (size_t)blockIdx.x * R + r;
    const f32x4* Ap = (const f32x4*)(A + n * 128);
    float acc = bias ? bias[o] : 0.f;
#pragma unroll 4
    for (int k8 = 0; k8 < 16; ++k8) {
        f16x8 wv = *(const f16x8*)&Wls[o * 136 + k8 * 8];
        f32x4 a0 = Ap[k8 * 2], a1 = Ap[k8 * 2 + 1];
        acc += (float)wv[0] * a0[0] + (float)wv[1] * a0[1] + (float)wv[2] * a0[2] + (float)wv[3] * a0[3]
             + (float)wv[4] * a1[0] + (float)wv[5] * a1[1] + (float)wv[6] * a1[2] + (float)wv[7] * a1[3];
    }
    float v = acc;
    if (act == 1) v = lrelu_(v);
    else if (act == 2) v = sigmoidf_(v);
    out[n * O + o] = v;
    if (rowsum) {
        float s = v;
#pragma unroll
        for (int m = 1; m < 32; m <<= 1) s += __shfl_xor(s, m);
        if (o == 0) rowsum[n] = s;
    }
}

// ---------------- edge reduce, stage 1: blocked outer-product partials ----------------
__global__ __launch_bounds__(256) void k_edge_part(const void* __restrict__ S, int isInt,
                                                   const float* __restrict__ X,
                                                   float* __restrict__ part,
                                                   float* __restrict__ d_e,
                                                   int E, int N, int rowsPerBlk)
{
    int tid = threadIdx.x;
    int pair = tid >> 7, c = tid & 127, lane = tid & 63;
    int JG = E >> 5;
    int jg, rOff, rStep;
    if (JG == 2) { jg = pair; rOff = 0; rStep = 1; }
    else         { jg = 0;    rOff = pair; rStep = 2; }
    int n0 = blockIdx.x * rowsPerBlk;
    int n1 = n0 + rowsPerBlk; if (n1 > N) n1 = N;
    const int* Si = (const int*)S; const float* Sf = (const float*)S;
    int js = jg * 32 + (lane & 31);

    float acc[32];
#pragma unroll
    for (int i = 0; i < 32; ++i) acc[i] = 0.f;
    float dcnt = 0.f;

    for (int n = n0 + rOff; n < n1; n += rStep) {
        float sval = isInt ? (float)Si[(size_t)n * E + js] : Sf[(size_t)n * E + js];
        float xc = X[(size_t)n * 128 + c];
        dcnt += sval;
        int sv = __float_as_int(sval);
#pragma unroll
        for (int jj = 0; jj < 32; ++jj) {
            float s = __int_as_float(__builtin_amdgcn_readlane(sv, jj));
            acc[jj] += s * xc;
        }
    }
    float* pp = part + ((size_t)(blockIdx.x * 2 + pair) * 32) * 128;
#pragma unroll
    for (int jj = 0; jj < 32; ++jj)
        pp[(size_t)jj * 128 + c] = acc[jj];
    int w = tid >> 6;
    if ((w & 1) == 0 && (lane & 32) == 0)
        atomicAdd(&d_e[jg * 32 + lane], dcnt);
}

// ---------------- edge reduce, stage 2: sum partials, scale by 1/d_e ----------------
__global__ __launch_bounds__(128) void k_edge_finish(const float* __restrict__ part,
                                                     const float* __restrict__ d_e,
                                                     float* __restrict__ m, int P, int JG)
{
    int j = blockIdx.x, c = threadIdx.x;
    float acc = 0.f;
    if (JG == 2) {
        int pair = j >> 5, jj = j & 31;
        for (int b = 0; b < P; ++b)
            acc += part[((size_t)(b * 2 + pair) * 32 + jj) * 128 + c];
    } else {
        for (int b = 0; b < 2 * P; ++b)
            acc += part[((size_t)b * 32 + j) * 128 + c];
    }
    float d = d_e[j];
    float s = d > 0.f ? 1.f / d : 0.f;
    m[j * 128 + c] = acc * s;
}

// ---------------- hconv apply ----------------
__global__ __launch_bounds__(256) void k_hconv_apply(const void* __restrict__ S, int isInt, int E,
                                                     const float* __restrict__ m,
                                                     const float* __restrict__ dn_pre, int sqrtMode,
                                                     const float* __restrict__ bias,
                                                     const float* __restrict__ base,
                                                     float* __restrict__ outMain,
                                                     float* __restrict__ outSub)
{
    __shared__ float mls[64 * 128];
    int tid = threadIdx.x;
    for (int idx = tid; idx < E * 128; idx += 256) mls[idx] = m[idx];
    __syncthreads();
    int c = tid & 127, r = tid >> 7;
    size_t n = (size_t)blockIdx.x * 2 + r;
    const int* Si = (const int*)S; const float* Sf = (const float*)S;
    float acc = 0.f, d = 0.f;
    for (int j = 0; j < E; ++j) {
        float s = isInt ? (float)Si[n * E + j] : Sf[n * E + j];
        acc += s * mls[j * 128 + c];
        d += s;
    }
    if (dn_pre) d = dn_pre[n];
    float sc = d > 0.f ? (sqrtMode ? rsqrtf(d) : 1.f / d) : 0.f;
    float v = acc * sc + (bias ? bias[c] : 0.f);
    v = lrelu_(v);
    outMain[n * 128 + c] = v;
    if (outSub) outSub[n * 128 + c] = base[n * 128 + c] - v;
}

// ---------------- final projection ----------------
__global__ __launch_bounds__(256) void k_final(const float* __restrict__ ep,
                                               const float* __restrict__ eh,
                                               const float* __restrict__ ea,
                                               const float* __restrict__ Wf,
                                               const float* __restrict__ bf,
                                               float* __restrict__ out, int N)
{
    int wv = threadIdx.x >> 6, lane = threadIdx.x & 63;
    int n = blockIdx.x * 4 + wv;
    if (n >= N) return;
    size_t base = (size_t)n * 128;
    float acc = ep[base + lane] * Wf[lane]       + ep[base + lane + 64] * Wf[lane + 64]
              + eh[base + lane] * Wf[128 + lane] + eh[base + lane + 64] * Wf[128 + lane + 64]
              + ea[base + lane] * Wf[256 + lane] + ea[base + lane + 64] * Wf[256 + lane + 64];
#pragma unroll
    for (int m2 = 1; m2 < 64; m2 <<= 1) acc += __shfl_xor(acc, m2);
    if (lane == 0) out[n] = acc + bf[0];
}

extern "C" void kernel_launch(void* const* d_in, const int* in_sizes, int n_in,
                              void* d_out, int out_size, void* d_ws, size_t ws_size,
                              hipStream_t stream)
{
    const float* x     = (const float*)d_in[0];
    const int*   Hp    = (const int*)d_in[1];
    const float* ln_g  = (const float*)d_in[2];
    const float* ln_b  = (const float*)d_in[3];
    const float* W_ih0 = (const float*)d_in[4];
    const float* W_hh0 = (const float*)d_in[5];
    const float* b_ih0 = (const float*)d_in[6];
    const float* b_hh0 = (const float*)d_in[7];
    const float* W_ih1 = (const float*)d_in[8];
    const float* W_hh1 = (const float*)d_in[9];
    const float* b_ih1 = (const float*)d_in[10];
    const float* b_hh1 = (const float*)d_in[11];
    const float* Wp    = (const float*)d_in[12];
    const float* bp    = (const float*)d_in[13];
    const float* prot  = (const float*)d_in[14];
    const float* Ws    = (const float*)d_in[15];
    const float* bs    = (const float*)d_in[16];
    const float* Wa    = (const float*)d_in[17];
    const float* ba    = (const float*)d_in[18];
    const float* Wf    = (const float*)d_in[19];
    const float* bf    = (const float*)d_in[20];
    float* out = (float*)d_out;
    (void)n_in; (void)out_size; (void)ws_size;

    const int T = 64, E = 64, K = 32;
    int N = in_sizes[0] / (T * 128);         // 4000
    size_t NT = (size_t)N * T;

    const int ROWS_PER_BLK = 16;
    int P = (N + ROWS_PER_BLK - 1) / ROWS_PER_BLK;   // 250

    char* ws = (char*)d_ws;
    size_t off = 0;
    auto alloc = [&](size_t bytes) { char* p = ws + off; off += (bytes + 255) & ~(size_t)255; return p; };
    _Float16* xn  = (_Float16*)alloc(NT * 128 * 2);
    float* e_s   = (float*)alloc((size_t)N * 128 * 4);
    float* t1    = (float*)alloc((size_t)N * 128 * 4);
    float* e_p   = (float*)alloc((size_t)N * 128 * 4);
    float* e_r   = (float*)alloc((size_t)N * 128 * 4);
    float* beta  = (float*)alloc((size_t)N * K * 4);
    float* dn2   = (float*)alloc((size_t)N * 4);
    float* xW    = (float*)alloc((size_t)N * 128 * 4);
    float* e_h   = (float*)alloc((size_t)N * 128 * 4);
    float* e_res = (float*)alloc((size_t)N * 128 * 4);
    float* e_al  = (float*)alloc((size_t)N * 128 * 4);
    float* part  = (float*)alloc((size_t)P * 2 * 32 * 128 * 4);   // 8 MB partials
    float* macc  = (float*)alloc((64 * 128 + 64 + 32 * 128 + 32) * 4);
    float* m_e  = macc;
    float* d_e  = macc + 64 * 128;
    float* m2   = d_e + 64;
    float* d_e2 = m2 + 32 * 128;

    k_ln<<<(int)(NT / 16), 256, 0, stream>>>(x, ln_g, ln_b, xn, N);
    k_gru2<<<N / 16, 512, 0, stream>>>(xn, W_ih0, W_hh0, b_ih0, b_hh0,
                                       W_ih1, W_hh1, b_ih1, b_hh1, e_s, N);

    hipMemsetAsync(macc, 0, (64 * 128 + 64 + 32 * 128 + 32) * 4, stream);
    k_mm128<<<N / 16, 512, 0, stream>>>(e_s, Wp, nullptr, t1, 0);
    k_edge_part<<<P, 256, 0, stream>>>(Hp, 1, t1, part, d_e, E, N, ROWS_PER_BLK);
    k_edge_finish<<<E, 128, 0, stream>>>(part, d_e, m_e, P, 2);
    k_hconv_apply<<<N / 2, 256, 0, stream>>>(Hp, 1, E, m_e, nullptr, 0, bp, e_s, e_p, e_r);

    k_mm128<<<N / 16, 512, 0, stream>>>(e_r, Ws, bs, xW, 0);
    k_mm<<<N / 8, 256, 0, stream>>>(e_r, prot, nullptr, beta, dn2, 32, 2);
    k_edge_part<<<P, 256, 0, stream>>>(beta, 0, xW, part, d_e2, K, N, ROWS_PER_BLK);
    k_edge_finish<<<K, 128, 0, stream>>>(part, d_e2, m2, P, 1);
    k_hconv_apply<<<N / 2, 256, 0, stream>>>(beta, 0, K, m2, dn2, 1, nullptr, e_r, e_h, e_res);

    k_mm128<<<N / 16, 512, 0, stream>>>(e_res, Wa, ba, e_al, 1);
    k_final<<<(N + 3) / 4, 256, 0, stream>>>(e_p, e_h, e_al, Wf, bf, out, N);
}

// Round 4
// 659.159 us; speedup vs baseline: 1.2354x; 1.0223x over previous
//
#include <hip/hip_runtime.h>
#include <hip/hip_fp16.h>

typedef float    f32x4 __attribute__((ext_vector_type(4)));
typedef _Float16 f16x8 __attribute__((ext_vector_type(8)));

__device__ __forceinline__ float sigmoidf_(float x) { return __builtin_amdgcn_rcpf(1.f + __expf(-x)); }
__device__ __forceinline__ float tanhf_(float x) { float e = __expf(2.f * x); return 1.f - 2.f * __builtin_amdgcn_rcpf(e + 1.f); }
__device__ __forceinline__ float lrelu_(float v) { return v > 0.f ? v : 0.01f * v; }

__device__ __forceinline__ f16x8 cvt8(const float* p) {
    const f32x4* q = (const f32x4*)p;
    f32x4 a = q[0], b = q[1];
    f16x8 v;
    v[0] = (_Float16)a[0]; v[1] = (_Float16)a[1]; v[2] = (_Float16)a[2]; v[3] = (_Float16)a[3];
    v[4] = (_Float16)b[0]; v[5] = (_Float16)b[1]; v[6] = (_Float16)b[2]; v[7] = (_Float16)b[3];
    return v;
}

__device__ __forceinline__ void gload_lds16(const void* g, void* l) {
    __builtin_amdgcn_global_load_lds(
        (const __attribute__((address_space(1))) void*)g,
        (__attribute__((address_space(3))) void*)l,
        16, 0, 0);
}

// ---------------- LayerNorm + cast to f16, TIME-MAJOR [T][N][128] ----------------
__global__ __launch_bounds__(256) void k_ln(const float* __restrict__ x,
                                            const float* __restrict__ g,
                                            const float* __restrict__ b,
                                            _Float16* __restrict__ xn, int N)
{
    int tid = threadIdx.x;
    int r = tid >> 4, i = tid & 15;
    size_t row = (size_t)blockIdx.x * 16 + r;          // row = n*64 + t
    int n = (int)(row >> 6), t = (int)(row & 63);
    const f32x4* xp = (const f32x4*)(x + row * 128 + i * 8);
    f32x4 a0 = xp[0], a1 = xp[1];
    float v0=a0[0], v1=a0[1], v2=a0[2], v3=a0[3], v4=a1[0], v5=a1[1], v6=a1[2], v7=a1[3];
    float s  = v0+v1+v2+v3+v4+v5+v6+v7;
    float s2 = v0*v0+v1*v1+v2*v2+v3*v3+v4*v4+v5*v5+v6*v6+v7*v7;
#pragma unroll
    for (int m = 1; m <= 8; m <<= 1) { s += __shfl_xor(s, m); s2 += __shfl_xor(s2, m); }
    float mu  = s * (1.f / 128.f);
    float var = s2 * (1.f / 128.f) - mu * mu;
    float rs  = rsqrtf(var + 1e-5f);
    const f32x4* gp = (const f32x4*)(g + i * 8);
    const f32x4* bp = (const f32x4*)(b + i * 8);
    f32x4 g0 = gp[0], g1 = gp[1], bb0 = bp[0], bb1 = bp[1];
    f16x8 o;
    o[0] = (_Float16)((v0 - mu) * rs * g0[0] + bb0[0]);
    o[1] = (_Float16)((v1 - mu) * rs * g0[1] + bb0[1]);
    o[2] = (_Float16)((v2 - mu) * rs * g0[2] + bb0[2]);
    o[3] = (_Float16)((v3 - mu) * rs * g0[3] + bb0[3]);
    o[4] = (_Float16)((v4 - mu) * rs * g1[0] + bb1[0]);
    o[5] = (_Float16)((v5 - mu) * rs * g1[1] + bb1[1]);
    o[6] = (_Float16)((v6 - mu) * rs * g1[2] + bb1[2]);
    o[7] = (_Float16)((v7 - mu) * rs * g1[3] + bb1[3]);
    *(f16x8*)(xn + ((size_t)t * N + n) * 128 + i * 8) = o;
}

// ---------------- Fused 2-layer GRU, slot-shifted, clustered-MFMA ----------------
// Slot s: L0(t=s) + L1(t=s-1). L1's inputs (h0[s-1], h1[s-1]) are available at
// slot START, so ALL 48 MFMAs issue as one cluster (8 independent acc chains)
// before any gate VALU -> matrix pipe never drains on the gate phases.
// One __syncthreads per slot. Weights: W_ih0 (96 KB) + W_hh0_r (32 KB) in LDS;
// W_hh0_{z,n} (32) + W_ih1 (48) + W_hh1 (48) = 128 regs. waves_per_eu(2) ->
// 256-reg unified budget -> no spills (r3: 35 MB/dispatch scratch writes).
__global__ __launch_bounds__(512) __attribute__((amdgpu_waves_per_eu(2)))
void k_gru2(const _Float16* __restrict__ xin,
            const float* __restrict__ W_ih0,
            const float* __restrict__ W_hh0,
            const float* __restrict__ b_ih0,
            const float* __restrict__ b_hh0,
            const float* __restrict__ W_ih1,
            const float* __restrict__ W_hh1,
            const float* __restrict__ b_ih1,
            const float* __restrict__ b_hh1,
            float* __restrict__ es, int N)
{
    __shared__ __align__(16) _Float16 wlds[96 * 64 * 8];     // 96 KB: W_ih0 fragments
    __shared__ __align__(16) _Float16 wldsr[32 * 64 * 8];    // 32 KB: W_hh0 r-gate fragments
    __shared__ __align__(16) _Float16 hbuf0[2][16 * 136];
    __shared__ __align__(16) _Float16 hbuf1[2][16 * 136];
    __shared__ __align__(16) _Float16 xls[2][16 * 128];      // linear, XOR-swizzled content

    int tid = threadIdx.x;
    int w = tid >> 6, lane = tid & 63;
    int ul = lane & 15, q = lane >> 4;
    int u = w * 16 + ul;
    int n0 = blockIdx.x * 16;

    // stage W_ih0 (all gates) and W_hh0 r-gate into LDS, fragment-ordered
#pragma unroll
    for (int g = 0; g < 3; ++g)
#pragma unroll
        for (int kt = 0; kt < 4; ++kt) {
            f16x8 v = cvt8(W_ih0 + (size_t)(u + g * 128) * 128 + kt * 32 + q * 8);
            *(f16x8*)&wlds[(size_t)((w * 12 + g * 4 + kt) * 64 + lane) * 8] = v;
        }
#pragma unroll
    for (int kt = 0; kt < 4; ++kt) {
        f16x8 v = cvt8(W_hh0 + (size_t)u * 128 + kt * 32 + q * 8);
        *(f16x8*)&wldsr[(size_t)((w * 4 + kt) * 64 + lane) * 8] = v;
    }
    const _Float16* wbase  = &wlds[(size_t)(w * 12 * 64 + lane) * 8];
    const _Float16* w0base = &wldsr[(size_t)(w * 4 * 64 + lane) * 8];

    // register weights: W_hh0 z/n, W_ih1, W_hh1
    f16x8 whh0zn[8], wih1[12], whh1[12];
#pragma unroll
    for (int kt = 0; kt < 4; ++kt) {
        whh0zn[kt]     = cvt8(W_hh0 + (size_t)(u + 128) * 128 + kt * 32 + q * 8);
        whh0zn[4 + kt] = cvt8(W_hh0 + (size_t)(u + 256) * 128 + kt * 32 + q * 8);
    }
#pragma unroll
    for (int g = 0; g < 3; ++g)
#pragma unroll
        for (int kt = 0; kt < 4; ++kt) {
            size_t roff = (size_t)(u + g * 128) * 128 + kt * 32 + q * 8;
            wih1[g * 4 + kt] = cvt8(W_ih1 + roff);
            whh1[g * 4 + kt] = cvt8(W_hh1 + roff);
        }
    float br0 = b_ih0[u] + b_hh0[u], bz0 = b_ih0[u + 128] + b_hh0[u + 128];
    float bin0 = b_ih0[u + 256], bhn0 = b_hh0[u + 256];
    float br1 = b_ih1[u] + b_hh1[u], bz1 = b_ih1[u + 128] + b_hh1[u + 128];
    float bin1 = b_ih1[u + 256], bhn1 = b_hh1[u + 256];

    for (int idx = tid; idx < 16 * 136; idx += 512) {
        hbuf0[0][idx] = (_Float16)0.f;
        hbuf1[0][idx] = (_Float16)0.f;
        hbuf1[1][idx] = (_Float16)0.f;
    }
    float h0j[4] = {0.f, 0.f, 0.f, 0.f}, h1j[4] = {0.f, 0.f, 0.f, 0.f};
    const f32x4 Z4 = {0.f, 0.f, 0.f, 0.f};

    // precomputed addressing
    int xoff[4];
#pragma unroll
    for (int kt = 0; kt < 4; ++kt)
        xoff[kt] = (ul * 256 + kt * 64 + q * 16) ^ ((ul & 7) << 4);
    int dlin = w * 1024 + (lane << 4);
    int dsrc = dlin ^ (((dlin >> 8) & 7) << 4);

#define PREF_X(T, PB)                                                                \
    if (w < 4) {                                                                     \
        const char* gsrc = (const char*)(xin + ((size_t)(T) * N + n0) * 128);        \
        gload_lds16(gsrc + dsrc, (void*)((char*)&xls[PB][0] + dlin));                \
    }

#define LOAD_HF(HF, BUF, PB)                                                         \
    { const _Float16* hb = &BUF[PB][ul * 136 + q * 8];                               \
      _Pragma("unroll")                                                              \
      for (int kt = 0; kt < 4; ++kt) HF[kt] = *(const f16x8*)(hb + kt * 32); }

    // L0 MFMA contribution for one kt (x streamed from LDS, weights from LDS/regs)
#define L0_KT(KT, XB)                                                                \
    {                                                                                \
        f16x8 xv  = *(const f16x8*)((XB) + xoff[KT]);                                \
        f16x8 wrv = *(const f16x8*)(wbase + (size_t)(KT) * 512);                     \
        f16x8 wzv = *(const f16x8*)(wbase + (size_t)(4 + (KT)) * 512);               \
        f16x8 wnv = *(const f16x8*)(wbase + (size_t)(8 + (KT)) * 512);               \
        f16x8 w0r = *(const f16x8*)(w0base + (size_t)(KT) * 512);                    \
        ar0  = __builtin_amdgcn_mfma_f32_16x16x32_f16(xv, wrv, ar0, 0, 0, 0);        \
        ar0  = __builtin_amdgcn_mfma_f32_16x16x32_f16(h0f[KT], w0r, ar0, 0, 0, 0);   \
        az0  = __builtin_amdgcn_mfma_f32_16x16x32_f16(xv, wzv, az0, 0, 0, 0);        \
        az0  = __builtin_amdgcn_mfma_f32_16x16x32_f16(h0f[KT], whh0zn[KT], az0, 0, 0, 0); \
        an0x = __builtin_amdgcn_mfma_f32_16x16x32_f16(xv, wnv, an0x, 0, 0, 0);       \
        an0h = __builtin_amdgcn_mfma_f32_16x16x32_f16(h0f[KT], whh0zn[4 + (KT)], an0h, 0, 0, 0); \
    }

#define L1_KT(KT)                                                                    \
    {                                                                                \
        ar1  = __builtin_amdgcn_mfma_f32_16x16x32_f16(h0f[KT], wih1[KT], ar1, 0, 0, 0); \
        ar1  = __builtin_amdgcn_mfma_f32_16x16x32_f16(h1f[KT], whh1[KT], ar1, 0, 0, 0); \
        az1  = __builtin_amdgcn_mfma_f32_16x16x32_f16(h0f[KT], wih1[4 + (KT)], az1, 0, 0, 0); \
        az1  = __builtin_amdgcn_mfma_f32_16x16x32_f16(h1f[KT], whh1[4 + (KT)], az1, 0, 0, 0); \
        an1x = __builtin_amdgcn_mfma_f32_16x16x32_f16(h0f[KT], wih1[8 + (KT)], an1x, 0, 0, 0); \
        an1h = __builtin_amdgcn_mfma_f32_16x16x32_f16(h1f[KT], whh1[8 + (KT)], an1h, 0, 0, 0); \
    }

#define GATES_L0(PW)                                                                 \
    { _Float16* wb = &hbuf0[PW][0];                                                  \
      _Pragma("unroll")                                                              \
      for (int j = 0; j < 4; ++j) {                                                  \
          float rr = sigmoidf_(ar0[j] + br0);                                        \
          float zz = sigmoidf_(az0[j] + bz0);                                        \
          float nn = tanhf_(an0x[j] + bin0 + rr * (an0h[j] + bhn0));                 \
          float hn = (1.f - zz) * nn + zz * h0j[j];                                  \
          h0j[j] = hn;                                                               \
          wb[(q * 4 + j) * 136 + u] = (_Float16)hn;                                  \
      } }

#define GATES_L1(PW)                                                                 \
    { _Float16* wb = &hbuf1[PW][0];                                                  \
      _Pragma("unroll")                                                              \
      for (int j = 0; j < 4; ++j) {                                                  \
          float rr = sigmoidf_(ar1[j] + br1);                                        \
          float zz = sigmoidf_(az1[j] + bz1);                                        \
          float nn = tanhf_(an1x[j] + bin1 + rr * (an1h[j] + bhn1));                 \
          float hn = (1.f - zz) * nn + zz * h1j[j];                                  \
          h1j[j] = hn;                                                               \
          wb[(q * 4 + j) * 136 + u] = (_Float16)hn;                                  \
      } }

    // prologue: stage x(0); weight staging + hbuf zero visible after barrier
    PREF_X(0, 0);
    __syncthreads();

    // slot 0: L0(t=0) only
    {
        PREF_X(1, 1);
        f16x8 h0f[4];
        LOAD_HF(h0f, hbuf0, 0);
        f32x4 ar0 = Z4, az0 = Z4, an0x = Z4, an0h = Z4;
        const char* xb = (const char*)&xls[0][0];
        L0_KT(0, xb) L0_KT(1, xb) L0_KT(2, xb) L0_KT(3, xb)
        GATES_L0(1);
        __syncthreads();
    }

    // slots 1..63: L0(t=s) + L1(t=s-1), one MFMA cluster, one barrier
    for (int s = 1; s < 64; ++s) {
        int P = s & 1;
        if (s < 63) { PREF_X(s + 1, P ^ 1); }
        f16x8 h0f[4], h1f[4];
        LOAD_HF(h0f, hbuf0, P);          // h0[s-1]: L0 h-operand AND L1 x-operand
        LOAD_HF(h1f, hbuf1, P);          // h1[s-1]
        f32x4 ar0 = Z4, az0 = Z4, an0x = Z4, an0h = Z4;
        f32x4 ar1 = Z4, az1 = Z4, an1x = Z4, an1h = Z4;
        const char* xb = (const char*)&xls[P][0];
        // 48-MFMA cluster: 8 independent accumulator chains
        L0_KT(0, xb) L1_KT(0)
        L0_KT(1, xb) L1_KT(1)
        L0_KT(2, xb) L1_KT(2)
        L0_KT(3, xb) L1_KT(3)
        GATES_L0(P ^ 1);
        GATES_L1(P ^ 1);
        __syncthreads();
    }

    // slot 64: L1(t=63) only (no LDS write needed)
    {
        f16x8 h0f[4], h1f[4];
        LOAD_HF(h0f, hbuf0, 0);          // h0[63] (slot 63, P=1, wrote buf 0)
        LOAD_HF(h1f, hbuf1, 0);          // h1[62]
        f32x4 ar1 = Z4, az1 = Z4, an1x = Z4, an1h = Z4;
        L1_KT(0) L1_KT(1) L1_KT(2) L1_KT(3)
#pragma unroll
        for (int j = 0; j < 4; ++j) {
            float rr = sigmoidf_(ar1[j] + br1);
            float zz = sigmoidf_(az1[j] + bz1);
            float nn = tanhf_(an1x[j] + bin1 + rr * (an1h[j] + bhn1));
            h1j[j] = (1.f - zz) * nn + zz * h1j[j];
        }
    }

#pragma unroll
    for (int j = 0; j < 4; ++j)
        es[(size_t)(n0 + q * 4 + j) * 128 + u] = h1j[j];

#undef PREF_X
#undef LOAD_HF
#undef L0_KT
#undef L1_KT
#undef GATES_L0
#undef GATES_L1
}

// ---------------- MFMA 128x128 matmul: out[n][o] = act(A[n,:]·W[o,:] + bias) ----------------
__global__ __launch_bounds__(512) void k_mm128(const float* __restrict__ A,
                                               const float* __restrict__ W,
                                               const float* __restrict__ bias,
                                               float* __restrict__ out, int act)
{
    int tid = threadIdx.x;
    int w = tid >> 6, lane = tid & 63;
    int ul = lane & 15, q = lane >> 4;
    int u = w * 16 + ul;
    int n0 = blockIdx.x * 16;

    f32x4 acc = {0.f, 0.f, 0.f, 0.f};
#pragma unroll
    for (int kt = 0; kt < 4; ++kt) {
        f16x8 af = cvt8(A + (size_t)(n0 + ul) * 128 + kt * 32 + q * 8);
        f16x8 wf = cvt8(W + (size_t)u * 128 + kt * 32 + q * 8);
        acc = __builtin_amdgcn_mfma_f32_16x16x32_f16(af, wf, acc, 0, 0, 0);
    }
    float bv = bias ? bias[u] : 0.f;
#pragma unroll
    for (int j = 0; j < 4; ++j) {
        float v = acc[j] + bv;
        if (act == 1) v = lrelu_(v);
        out[(size_t)(n0 + q * 4 + j) * 128 + u] = v;
    }
}

// ---------------- Generic small matmul (O=32 path: beta + rowsum) ----------------
__global__ __launch_bounds__(256) void k_mm(const float* __restrict__ A,
                                            const float* __restrict__ W,
                                            const float* __restrict__ bias,
                                            float* __restrict__ out,
                                            float* __restrict__ rowsum,
                                            int O, int act)
{
    __shared__ __align__(16) _Float16 Wls[128 * 136];
    int tid = threadIdx.x;
    int total = O * 128;
    for (int idx = tid; idx < total; idx += 256) {
        int o = idx >> 7, k = idx & 127;
        Wls[o * 136 + k] = (_Float16)W[idx];
    }
    __syncthreads();
    int o = tid & (O - 1);
    int r = tid / O;
    int R = 256 / O;
    size_t n = (size_t)blockIdx.x * R + r;
    const f32x4* Ap = (const f32x4*)(A + n * 128);
    float acc = bias ? bias[o] : 0.f;
#pragma unroll 4
    for (int k8 = 0; k8 < 16; ++k8) {
        f16x8 wv = *(const f16x8*)&Wls[o * 136 + k8 * 8];
        f32x4 a0 = Ap[k8 * 2], a1 = Ap[k8 * 2 + 1];
        acc += (float)wv[0] * a0[0] + (float)wv[1] * a0[1] + (float)wv[2] * a0[2] + (float)wv[3] * a0[3]
             + (float)wv[4] * a1[0] + (float)wv[5] * a1[1] + (float)wv[6] * a1[2] + (float)wv[7] * a1[3];
    }
    float v = acc;
    if (act == 1) v = lrelu_(v);
    else if (act == 2) v = sigmoidf_(v);
    out[n * O + o] = v;
    if (rowsum) {
        float s = v;
#pragma unroll
        for (int m = 1; m < 32; m <<= 1) s += __shfl_xor(s, m);
        if (o == 0) rowsum[n] = s;
    }
}

// ---------------- edge reduce, stage 1: blocked outer-product partials ----------------
__global__ __launch_bounds__(256) void k_edge_part(const void* __restrict__ S, int isInt,
                                                   const float* __restrict__ X,
                                                   float* __restrict__ part,
                                                   float* __restrict__ d_e,
                                                   int E, int N, int rowsPerBlk)
{
    int tid = threadIdx.x;
    int pair = tid >> 7, c = tid & 127, lane = tid & 63;
    int JG = E >> 5;
    int jg, rOff, rStep;
    if (JG == 2) { jg = pair; rOff = 0; rStep = 1; }
    else         { jg = 0;    rOff = pair; rStep = 2; }
    int n0 = blockIdx.x * rowsPerBlk;
    int n1 = n0 + rowsPerBlk; if (n1 > N) n1 = N;
    const int* Si = (const int*)S; const float* Sf = (const float*)S;
    int js = jg * 32 + (lane & 31);

    float acc[32];
#pragma unroll
    for (int i = 0; i < 32; ++i) acc[i] = 0.f;
    float dcnt = 0.f;

    for (int n = n0 + rOff; n < n1; n += rStep) {
        float sval = isInt ? (float)Si[(size_t)n * E + js] : Sf[(size_t)n * E + js];
        float xc = X[(size_t)n * 128 + c];
        dcnt += sval;
        int sv = __float_as_int(sval);
#pragma unroll
        for (int jj = 0; jj < 32; ++jj) {
            float s = __int_as_float(__builtin_amdgcn_readlane(sv, jj));
            acc[jj] += s * xc;
        }
    }
    float* pp = part + ((size_t)(blockIdx.x * 2 + pair) * 32) * 128;
#pragma unroll
    for (int jj = 0; jj < 32; ++jj)
        pp[(size_t)jj * 128 + c] = acc[jj];
    int w = tid >> 6;
    if ((w & 1) == 0 && (lane & 32) == 0)
        atomicAdd(&d_e[jg * 32 + lane], dcnt);
}

// ---------------- edge reduce, stage 2: sum partials, scale by 1/d_e ----------------
__global__ __launch_bounds__(128) void k_edge_finish(const float* __restrict__ part,
                                                     const float* __restrict__ d_e,
                                                     float* __restrict__ m, int P, int JG)
{
    int j = blockIdx.x, c = threadIdx.x;
    float acc = 0.f;
    if (JG == 2) {
        int pair = j >> 5, jj = j & 31;
        for (int b = 0; b < P; ++b)
            acc += part[((size_t)(b * 2 + pair) * 32 + jj) * 128 + c];
    } else {
        for (int b = 0; b < 2 * P; ++b)
            acc += part[((size_t)b * 32 + j) * 128 + c];
    }
    float d = d_e[j];
    float s = d > 0.f ? 1.f / d : 0.f;
    m[j * 128 + c] = acc * s;
}

// ---------------- hconv apply ----------------
__global__ __launch_bounds__(256) void k_hconv_apply(const void* __restrict__ S, int isInt, int E,
                                                     const float* __restrict__ m,
                                                     const float* __restrict__ dn_pre, int sqrtMode,
                                                     const float* __restrict__ bias,
                                                     const float* __restrict__ base,
                                                     float* __restrict__ outMain,
                                                     float* __restrict__ outSub)
{
    __shared__ float mls[64 * 128];
    int tid = threadIdx.x;
    for (int idx = tid; idx < E * 128; idx += 256) mls[idx] = m[idx];
    __syncthreads();
    int c = tid & 127, r = tid >> 7;
    size_t n = (size_t)blockIdx.x * 2 + r;
    const int* Si = (const int*)S; const float* Sf = (const float*)S;
    float acc = 0.f, d = 0.f;
    for (int j = 0; j < E; ++j) {
        float s = isInt ? (float)Si[n * E + j] : Sf[n * E + j];
        acc += s * mls[j * 128 + c];
        d += s;
    }
    if (dn_pre) d = dn_pre[n];
    float sc = d > 0.f ? (sqrtMode ? rsqrtf(d) : 1.f / d) : 0.f;
    float v = acc * sc + (bias ? bias[c] : 0.f);
    v = lrelu_(v);
    outMain[n * 128 + c] = v;
    if (outSub) outSub[n * 128 + c] = base[n * 128 + c] - v;
}

// ---------------- final projection ----------------
__global__ __launch_bounds__(256) void k_final(const float* __restrict__ ep,
                                               const float* __restrict__ eh,
                                               const float* __restrict__ ea,
                                               const float* __restrict__ Wf,
                                               const float* __restrict__ bf,
                                               float* __restrict__ out, int N)
{
    int wv = threadIdx.x >> 6, lane = threadIdx.x & 63;
    int n = blockIdx.x * 4 + wv;
    if (n >= N) return;
    size_t base = (size_t)n * 128;
    float acc = ep[base + lane] * Wf[lane]       + ep[base + lane + 64] * Wf[lane + 64]
              + eh[base + lane] * Wf[128 + lane] + eh[base + lane + 64] * Wf[128 + lane + 64]
              + ea[base + lane] * Wf[256 + lane] + ea[base + lane + 64] * Wf[256 + lane + 64];
#pragma unroll
    for (int m2 = 1; m2 < 64; m2 <<= 1) acc += __shfl_xor(acc, m2);
    if (lane == 0) out[n] = acc + bf[0];
}

extern "C" void kernel_launch(void* const* d_in, const int* in_sizes, int n_in,
                              void* d_out, int out_size, void* d_ws, size_t ws_size,
                              hipStream_t stream)
{
    const float* x     = (const float*)d_in[0];
    const int*   Hp    = (const int*)d_in[1];
    const float* ln_g  = (const float*)d_in[2];
    const float* ln_b  = (const float*)d_in[3];
    const float* W_ih0 = (const float*)d_in[4];
    const float* W_hh0 = (const float*)d_in[5];
    const float* b_ih0 = (const float*)d_in[6];
    const float* b_hh0 = (const float*)d_in[7];
    const float* W_ih1 = (const float*)d_in[8];
    const float* W_hh1 = (const float*)d_in[9];
    const float* b_ih1 = (const float*)d_in[10];
    const float* b_hh1 = (const float*)d_in[11];
    const float* Wp    = (const float*)d_in[12];
    const float* bp    = (const float*)d_in[13];
    const float* prot  = (const float*)d_in[14];
    const float* Ws    = (const float*)d_in[15];
    const float* bs    = (const float*)d_in[16];
    const float* Wa    = (const float*)d_in[17];
    const float* ba    = (const float*)d_in[18];
    const float* Wf    = (const float*)d_in[19];
    const float* bf    = (const float*)d_in[20];
    float* out = (float*)d_out;
    (void)n_in; (void)out_size; (void)ws_size;

    const int T = 64, E = 64, K = 32;
    int N = in_sizes[0] / (T * 128);         // 4000
    size_t NT = (size_t)N * T;

    const int ROWS_PER_BLK = 16;
    int P = (N + ROWS_PER_BLK - 1) / ROWS_PER_BLK;   // 250

    char* ws = (char*)d_ws;
    size_t off = 0;
    auto alloc = [&](size_t bytes) { char* p = ws + off; off += (bytes + 255) & ~(size_t)255; return p; };
    _Float16* xn  = (_Float16*)alloc(NT * 128 * 2);
    float* e_s   = (float*)alloc((size_t)N * 128 * 4);
    float* t1    = (float*)alloc((size_t)N * 128 * 4);
    float* e_p   = (float*)alloc((size_t)N * 128 * 4);
    float* e_r   = (float*)alloc((size_t)N * 128 * 4);
    float* beta  = (float*)alloc((size_t)N * K * 4);
    float* dn2   = (float*)alloc((size_t)N * 4);
    float* xW    = (float*)alloc((size_t)N * 128 * 4);
    float* e_h   = (float*)alloc((size_t)N * 128 * 4);
    float* e_res = (float*)alloc((size_t)N * 128 * 4);
    float* e_al  = (float*)alloc((size_t)N * 128 * 4);
    float* part  = (float*)alloc((size_t)P * 2 * 32 * 128 * 4);   // 8 MB partials
    float* macc  = (float*)alloc((64 * 128 + 64 + 32 * 128 + 32) * 4);
    float* m_e  = macc;
    float* d_e  = macc + 64 * 128;
    float* m2   = d_e + 64;
    float* d_e2 = m2 + 32 * 128;

    k_ln<<<(int)(NT / 16), 256, 0, stream>>>(x, ln_g, ln_b, xn, N);
    k_gru2<<<N / 16, 512, 0, stream>>>(xn, W_ih0, W_hh0, b_ih0, b_hh0,
                                       W_ih1, W_hh1, b_ih1, b_hh1, e_s, N);

    hipMemsetAsync(macc, 0, (64 * 128 + 64 + 32 * 128 + 32) * 4, stream);
    k_mm128<<<N / 16, 512, 0, stream>>>(e_s, Wp, nullptr, t1, 0);
    k_edge_part<<<P, 256, 0, stream>>>(Hp, 1, t1, part, d_e, E, N, ROWS_PER_BLK);
    k_edge_finish<<<E, 128, 0, stream>>>(part, d_e, m_e, P, 2);
    k_hconv_apply<<<N / 2, 256, 0, stream>>>(Hp, 1, E, m_e, nullptr, 0, bp, e_s, e_p, e_r);

    k_mm128<<<N / 16, 512, 0, stream>>>(e_r, Ws, bs, xW, 0);
    k_mm<<<N / 8, 256, 0, stream>>>(e_r, prot, nullptr, beta, dn2, 32, 2);
    k_edge_part<<<P, 256, 0, stream>>>(beta, 0, xW, part, d_e2, K, N, ROWS_PER_BLK);
    k_edge_finish<<<K, 128, 0, stream>>>(part, d_e2, m2, P, 1);
    k_hconv_apply<<<N / 2, 256, 0, stream>>>(beta, 0, K, m2, dn2, 1, nullptr, e_r, e_h, e_res);

    k_mm128<<<N / 16, 512, 0, stream>>>(e_res, Wa, ba, e_al, 1);
    k_final<<<(N + 3) / 4, 256, 0, stream>>>(e_p, e_h, e_al, Wf, bf, out, N);
}

// Round 6
// 432.475 us; speedup vs baseline: 1.8829x; 1.5242x over previous
//
#include <hip/hip_runtime.h>
#include <hip/hip_fp16.h>

typedef float    f32x4 __attribute__((ext_vector_type(4)));
typedef _Float16 f16x8 __attribute__((ext_vector_type(8)));

__device__ __forceinline__ float sigmoidf_(float x) { return __builtin_amdgcn_rcpf(1.f + __expf(-x)); }
__device__ __forceinline__ float tanhf_(float x) { float e = __expf(2.f * x); return 1.f - 2.f * __builtin_amdgcn_rcpf(e + 1.f); }
__device__ __forceinline__ float lrelu_(float v) { return v > 0.f ? v : 0.01f * v; }

__device__ __forceinline__ f16x8 cvt8(const float* p) {
    const f32x4* q = (const f32x4*)p;
    f32x4 a = q[0], b = q[1];
    f16x8 v;
    v[0] = (_Float16)a[0]; v[1] = (_Float16)a[1]; v[2] = (_Float16)a[2]; v[3] = (_Float16)a[3];
    v[4] = (_Float16)b[0]; v[5] = (_Float16)b[1]; v[6] = (_Float16)b[2]; v[7] = (_Float16)b[3];
    return v;
}

__device__ __forceinline__ void gload_lds16(const void* g, void* l) {
    __builtin_amdgcn_global_load_lds(
        (const __attribute__((address_space(1))) void*)g,
        (__attribute__((address_space(3))) void*)l,
        16, 0, 0);
}

// ---------------- LayerNorm + cast to f16, TIME-MAJOR [T][N][128] ----------------
__global__ __launch_bounds__(256) void k_ln(const float* __restrict__ x,
                                            const float* __restrict__ g,
                                            const float* __restrict__ b,
                                            _Float16* __restrict__ xn, int N)
{
    int tid = threadIdx.x;
    int r = tid >> 4, i = tid & 15;
    size_t row = (size_t)blockIdx.x * 16 + r;          // row = n*64 + t
    int n = (int)(row >> 6), t = (int)(row & 63);
    const f32x4* xp = (const f32x4*)(x + row * 128 + i * 8);
    f32x4 a0 = xp[0], a1 = xp[1];
    float v0=a0[0], v1=a0[1], v2=a0[2], v3=a0[3], v4=a1[0], v5=a1[1], v6=a1[2], v7=a1[3];
    float s  = v0+v1+v2+v3+v4+v5+v6+v7;
    float s2 = v0*v0+v1*v1+v2*v2+v3*v3+v4*v4+v5*v5+v6*v6+v7*v7;
#pragma unroll
    for (int m = 1; m <= 8; m <<= 1) { s += __shfl_xor(s, m); s2 += __shfl_xor(s2, m); }
    float mu  = s * (1.f / 128.f);
    float var = s2 * (1.f / 128.f) - mu * mu;
    float rs  = rsqrtf(var + 1e-5f);
    const f32x4* gp = (const f32x4*)(g + i * 8);
    const f32x4* bp = (const f32x4*)(b + i * 8);
    f32x4 g0 = gp[0], g1 = gp[1], bb0 = bp[0], bb1 = bp[1];
    f16x8 o;
    o[0] = (_Float16)((v0 - mu) * rs * g0[0] + bb0[0]);
    o[1] = (_Float16)((v1 - mu) * rs * g0[1] + bb0[1]);
    o[2] = (_Float16)((v2 - mu) * rs * g0[2] + bb0[2]);
    o[3] = (_Float16)((v3 - mu) * rs * g0[3] + bb0[3]);
    o[4] = (_Float16)((v4 - mu) * rs * g1[0] + bb1[0]);
    o[5] = (_Float16)((v5 - mu) * rs * g1[1] + bb1[1]);
    o[6] = (_Float16)((v6 - mu) * rs * g1[2] + bb1[2]);
    o[7] = (_Float16)((v7 - mu) * rs * g1[3] + bb1[3]);
    *(f16x8*)(xn + ((size_t)t * N + n) * 128 + i * 8) = o;
}

// ---------------- Fused 2-layer GRU, slot-shifted, clustered-MFMA ----------------
__global__ __launch_bounds__(512) __attribute__((amdgpu_waves_per_eu(2)))
void k_gru2(const _Float16* __restrict__ xin,
            const float* __restrict__ W_ih0,
            const float* __restrict__ W_hh0,
            const float* __restrict__ b_ih0,
            const float* __restrict__ b_hh0,
            const float* __restrict__ W_ih1,
            const float* __restrict__ W_hh1,
            const float* __restrict__ b_ih1,
            const float* __restrict__ b_hh1,
            float* __restrict__ es, int N)
{
    __shared__ __align__(16) _Float16 wlds[96 * 64 * 8];     // 96 KB: W_ih0 fragments
    __shared__ __align__(16) _Float16 wldsr[32 * 64 * 8];    // 32 KB: W_hh0 r-gate fragments
    __shared__ __align__(16) _Float16 hbuf0[2][16 * 136];
    __shared__ __align__(16) _Float16 hbuf1[2][16 * 136];
    __shared__ __align__(16) _Float16 xls[2][16 * 128];      // linear, XOR-swizzled content

    int tid = threadIdx.x;
    int w = tid >> 6, lane = tid & 63;
    int ul = lane & 15, q = lane >> 4;
    int u = w * 16 + ul;
    int n0 = blockIdx.x * 16;

#pragma unroll
    for (int g = 0; g < 3; ++g)
#pragma unroll
        for (int kt = 0; kt < 4; ++kt) {
            f16x8 v = cvt8(W_ih0 + (size_t)(u + g * 128) * 128 + kt * 32 + q * 8);
            *(f16x8*)&wlds[(size_t)((w * 12 + g * 4 + kt) * 64 + lane) * 8] = v;
        }
#pragma unroll
    for (int kt = 0; kt < 4; ++kt) {
        f16x8 v = cvt8(W_hh0 + (size_t)u * 128 + kt * 32 + q * 8);
        *(f16x8*)&wldsr[(size_t)((w * 4 + kt) * 64 + lane) * 8] = v;
    }
    const _Float16* wbase  = &wlds[(size_t)(w * 12 * 64 + lane) * 8];
    const _Float16* w0base = &wldsr[(size_t)(w * 4 * 64 + lane) * 8];

    f16x8 whh0zn[8], wih1[12], whh1[12];
#pragma unroll
    for (int kt = 0; kt < 4; ++kt) {
        whh0zn[kt]     = cvt8(W_hh0 + (size_t)(u + 128) * 128 + kt * 32 + q * 8);
        whh0zn[4 + kt] = cvt8(W_hh0 + (size_t)(u + 256) * 128 + kt * 32 + q * 8);
    }
#pragma unroll
    for (int g = 0; g < 3; ++g)
#pragma unroll
        for (int kt = 0; kt < 4; ++kt) {
            size_t roff = (size_t)(u + g * 128) * 128 + kt * 32 + q * 8;
            wih1[g * 4 + kt] = cvt8(W_ih1 + roff);
            whh1[g * 4 + kt] = cvt8(W_hh1 + roff);
        }
    float br0 = b_ih0[u] + b_hh0[u], bz0 = b_ih0[u + 128] + b_hh0[u + 128];
    float bin0 = b_ih0[u + 256], bhn0 = b_hh0[u + 256];
    float br1 = b_ih1[u] + b_hh1[u], bz1 = b_ih1[u + 128] + b_hh1[u + 128];
    float bin1 = b_ih1[u + 256], bhn1 = b_hh1[u + 256];

    for (int idx = tid; idx < 16 * 136; idx += 512) {
        hbuf0[0][idx] = (_Float16)0.f;
        hbuf1[0][idx] = (_Float16)0.f;
        hbuf1[1][idx] = (_Float16)0.f;
    }
    float h0j[4] = {0.f, 0.f, 0.f, 0.f}, h1j[4] = {0.f, 0.f, 0.f, 0.f};
    const f32x4 Z4 = {0.f, 0.f, 0.f, 0.f};

    int xoff[4];
#pragma unroll
    for (int kt = 0; kt < 4; ++kt)
        xoff[kt] = (ul * 256 + kt * 64 + q * 16) ^ ((ul & 7) << 4);
    int dlin = w * 1024 + (lane << 4);
    int dsrc = dlin ^ (((dlin >> 8) & 7) << 4);

#define PREF_X(T, PB)                                                                \
    if (w < 4) {                                                                     \
        const char* gsrc = (const char*)(xin + ((size_t)(T) * N + n0) * 128);        \
        gload_lds16(gsrc + dsrc, (void*)((char*)&xls[PB][0] + dlin));                \
    }

#define LOAD_HF(HF, BUF, PB)                                                         \
    { const _Float16* hb = &BUF[PB][ul * 136 + q * 8];                               \
      _Pragma("unroll")                                                              \
      for (int kt = 0; kt < 4; ++kt) HF[kt] = *(const f16x8*)(hb + kt * 32); }

#define L0_KT(KT, XB)                                                                \
    {                                                                                \
        f16x8 xv  = *(const f16x8*)((XB) + xoff[KT]);                                \
        f16x8 wrv = *(const f16x8*)(wbase + (size_t)(KT) * 512);                     \
        f16x8 wzv = *(const f16x8*)(wbase + (size_t)(4 + (KT)) * 512);               \
        f16x8 wnv = *(const f16x8*)(wbase + (size_t)(8 + (KT)) * 512);               \
        f16x8 w0r = *(const f16x8*)(w0base + (size_t)(KT) * 512);                    \
        ar0  = __builtin_amdgcn_mfma_f32_16x16x32_f16(xv, wrv, ar0, 0, 0, 0);        \
        ar0  = __builtin_amdgcn_mfma_f32_16x16x32_f16(h0f[KT], w0r, ar0, 0, 0, 0);   \
        az0  = __builtin_amdgcn_mfma_f32_16x16x32_f16(xv, wzv, az0, 0, 0, 0);        \
        az0  = __builtin_amdgcn_mfma_f32_16x16x32_f16(h0f[KT], whh0zn[KT], az0, 0, 0, 0); \
        an0x = __builtin_amdgcn_mfma_f32_16x16x32_f16(xv, wnv, an0x, 0, 0, 0);       \
        an0h = __builtin_amdgcn_mfma_f32_16x16x32_f16(h0f[KT], whh0zn[4 + (KT)], an0h, 0, 0, 0); \
    }

#define L1_KT(KT)                                                                    \
    {                                                                                \
        ar1  = __builtin_amdgcn_mfma_f32_16x16x32_f16(h0f[KT], wih1[KT], ar1, 0, 0, 0); \
        ar1  = __builtin_amdgcn_mfma_f32_16x16x32_f16(h1f[KT], whh1[KT], ar1, 0, 0, 0); \
        az1  = __builtin_amdgcn_mfma_f32_16x16x32_f16(h0f[KT], wih1[4 + (KT)], az1, 0, 0, 0); \
        az1  = __builtin_amdgcn_mfma_f32_16x16x32_f16(h1f[KT], whh1[4 + (KT)], az1, 0, 0, 0); \
        an1x = __builtin_amdgcn_mfma_f32_16x16x32_f16(h0f[KT], wih1[8 + (KT)], an1x, 0, 0, 0); \
        an1h = __builtin_amdgcn_mfma_f32_16x16x32_f16(h1f[KT], whh1[8 + (KT)], an1h, 0, 0, 0); \
    }

#define GATES_L0(PW)                                                                 \
    { _Float16* wb = &hbuf0[PW][0];                                                  \
      _Pragma("unroll")                                                              \
      for (int j = 0; j < 4; ++j) {                                                  \
          float rr = sigmoidf_(ar0[j] + br0);                                        \
          float zz = sigmoidf_(az0[j] + bz0);                                        \
          float nn = tanhf_(an0x[j] + bin0 + rr * (an0h[j] + bhn0));                 \
          float hn = (1.f - zz) * nn + zz * h0j[j];                                  \
          h0j[j] = hn;                                                               \
          wb[(q * 4 + j) * 136 + u] = (_Float16)hn;                                  \
      } }

#define GATES_L1(PW)                                                                 \
    { _Float16* wb = &hbuf1[PW][0];                                                  \
      _Pragma("unroll")                                                              \
      for (int j = 0; j < 4; ++j) {                                                  \
          float rr = sigmoidf_(ar1[j] + br1);                                        \
          float zz = sigmoidf_(az1[j] + bz1);                                        \
          float nn = tanhf_(an1x[j] + bin1 + rr * (an1h[j] + bhn1));                 \
          float hn = (1.f - zz) * nn + zz * h1j[j];                                  \
          h1j[j] = hn;                                                               \
          wb[(q * 4 + j) * 136 + u] = (_Float16)hn;                                  \
      } }

    PREF_X(0, 0);
    __syncthreads();

    {
        PREF_X(1, 1);
        f16x8 h0f[4];
        LOAD_HF(h0f, hbuf0, 0);
        f32x4 ar0 = Z4, az0 = Z4, an0x = Z4, an0h = Z4;
        const char* xb = (const char*)&xls[0][0];
        L0_KT(0, xb) L0_KT(1, xb) L0_KT(2, xb) L0_KT(3, xb)
        GATES_L0(1);
        __syncthreads();
    }

    for (int s = 1; s < 64; ++s) {
        int P = s & 1;
        if (s < 63) { PREF_X(s + 1, P ^ 1); }
        f16x8 h0f[4], h1f[4];
        LOAD_HF(h0f, hbuf0, P);
        LOAD_HF(h1f, hbuf1, P);
        f32x4 ar0 = Z4, az0 = Z4, an0x = Z4, an0h = Z4;
        f32x4 ar1 = Z4, az1 = Z4, an1x = Z4, an1h = Z4;
        const char* xb = (const char*)&xls[P][0];
        L0_KT(0, xb) L1_KT(0)
        L0_KT(1, xb) L1_KT(1)
        L0_KT(2, xb) L1_KT(2)
        L0_KT(3, xb) L1_KT(3)
        GATES_L0(P ^ 1);
        GATES_L1(P ^ 1);
        __syncthreads();
    }

    {
        f16x8 h0f[4], h1f[4];
        LOAD_HF(h0f, hbuf0, 0);
        LOAD_HF(h1f, hbuf1, 0);
        f32x4 ar1 = Z4, az1 = Z4, an1x = Z4, an1h = Z4;
        L1_KT(0) L1_KT(1) L1_KT(2) L1_KT(3)
#pragma unroll
        for (int j = 0; j < 4; ++j) {
            float rr = sigmoidf_(ar1[j] + br1);
            float zz = sigmoidf_(az1[j] + bz1);
            float nn = tanhf_(an1x[j] + bin1 + rr * (an1h[j] + bhn1));
            h1j[j] = (1.f - zz) * nn + zz * h1j[j];
        }
    }

#pragma unroll
    for (int j = 0; j < 4; ++j)
        es[(size_t)(n0 + q * 4 + j) * 128 + u] = h1j[j];

#undef PREF_X
#undef LOAD_HF
#undef L0_KT
#undef L1_KT
#undef GATES_L0
#undef GATES_L1
}

// ================== shared macros for the post-GRU kernels ==================
#define STAGE_W(SRC)                                                                  \
    _Pragma("unroll")                                                                 \
    for (int tile = 0; tile < 2; ++tile)                                              \
    _Pragma("unroll")                                                                 \
    for (int kt = 0; kt < 4; ++kt) {                                                  \
        f16x8 v = cvt8((SRC) + (size_t)(w * 32 + tile * 16 + ul) * 128 + kt * 32 + q * 8); \
        *(f16x8*)&wfr[(size_t)(((w * 2 + tile) * 4 + kt) * 64 + lane) * 8] = v;       \
    }

#define LOAD_AF(AF, TF)                                                               \
    _Pragma("unroll")                                                                 \
    for (int kt = 0; kt < 4; ++kt) AF[kt] = cvt8(&TF[ul][kt * 32 + q * 8]);

#define MM128T(AF, A0, A1)                                                            \
    _Pragma("unroll")                                                                 \
    for (int kt = 0; kt < 4; ++kt) {                                                  \
        f16x8 b0 = *(const f16x8*)&wfr[(size_t)(((w * 2 + 0) * 4 + kt) * 64 + lane) * 8]; \
        f16x8 b1 = *(const f16x8*)&wfr[(size_t)(((w * 2 + 1) * 4 + kt) * 64 + lane) * 8]; \
        A0 = __builtin_amdgcn_mfma_f32_16x16x32_f16(AF[kt], b0, A0, 0, 0, 0);         \
        A1 = __builtin_amdgcn_mfma_f32_16x16x32_f16(AF[kt], b1, A1, 0, 0, 0);         \
    }

#define STAGE_ROWS16(DST, SRC)                                                        \
    { int r_ = tid >> 4, i_ = tid & 15;                                               \
      const f32x4* sp_ = (const f32x4*)((SRC) + (size_t)(n0 + r_) * 128 + i_ * 8);    \
      f32x4 a_ = sp_[0], b_ = sp_[1];                                                 \
      *(f32x4*)&DST[r_][i_ * 8] = a_;                                                 \
      *(f32x4*)&DST[r_][i_ * 8 + 4] = b_; }

// ---- kA: t1 = e_s @ Wp^T (LDS only); edge partials -> atomicAdd macc_e/d_e ----
__global__ __launch_bounds__(256) void k_postA(
    const float* __restrict__ e_s, const int* __restrict__ Hp,
    const float* __restrict__ Wp,
    float* __restrict__ macc_e, float* __restrict__ d_e)
{
    __shared__ __align__(16) _Float16 wfr[32 * 64 * 8];
    __shared__ float esf[16][132], xwf[16][132];
    int tid = threadIdx.x;
    int w = tid >> 6, lane = tid & 63;
    int ul = lane & 15, q = lane >> 4;
    int n0 = blockIdx.x * 16;
    const f32x4 Z4 = {0.f, 0.f, 0.f, 0.f};

    STAGE_W(Wp);
    STAGE_ROWS16(esf, e_s);
    __syncthreads();
    {
        f16x8 af[4]; LOAD_AF(af, esf);
        f32x4 a0 = Z4, a1 = Z4;
        MM128T(af, a0, a1);
#pragma unroll
        for (int j = 0; j < 4; ++j) {
            xwf[q * 4 + j][w * 32 + ul]      = a0[j];
            xwf[q * 4 + j][w * 32 + 16 + ul] = a1[j];
        }
    }
    __syncthreads();
    {
        int pair = tid >> 7, c = tid & 127;
        int js = pair * 32 + (lane & 31);
        float acc[32];
#pragma unroll
        for (int i = 0; i < 32; ++i) acc[i] = 0.f;
        float dcnt = 0.f;
        for (int r = 0; r < 16; ++r) {
            float sval = (float)Hp[(size_t)(n0 + r) * 64 + js];
            float xc = xwf[r][c];
            dcnt += sval;
            int sv = __float_as_int(sval);
#pragma unroll
            for (int jj = 0; jj < 32; ++jj)
                acc[jj] += __int_as_float(__builtin_amdgcn_readlane(sv, jj)) * xc;
        }
#pragma unroll
        for (int jj = 0; jj < 32; ++jj)
            atomicAdd(&macc_e[(size_t)(pair * 32 + jj) * 128 + c], acc[jj]);
        if ((w & 1) == 0 && (lane & 32) == 0)
            atomicAdd(&d_e[pair * 32 + lane], dcnt);
    }
}

// ---- kC: e_p/e_r; xW = e_r@Ws+bs; beta = sig(e_r@prot); dn; partials-2 ----
__global__ __launch_bounds__(256) void k_postC(
    const float* __restrict__ e_s, const int* __restrict__ Hp,
    const float* __restrict__ bp, const float* __restrict__ prot,
    const float* __restrict__ Ws, const float* __restrict__ bs,
    const float* __restrict__ macc_e, const float* __restrict__ d_e,
    float* __restrict__ ep_g, float* __restrict__ er_g,
    float* __restrict__ beta_g, float* __restrict__ dn_g,
    float* __restrict__ macc_2, float* __restrict__ d_e2)
{
    __shared__ __align__(16) _Float16 wfr[32 * 64 * 8];
    __shared__ __align__(16) _Float16 pfr[8 * 64 * 8];
    __shared__ float mst[64 * 128];
    __shared__ float esf[16][132], erf[16][132], xwf[16][132];
    __shared__ float betaf[16][36];
    int tid = threadIdx.x;
    int w = tid >> 6, lane = tid & 63;
    int ul = lane & 15, q = lane >> 4;
    int n0 = blockIdx.x * 16;
    const f32x4 Z4 = {0.f, 0.f, 0.f, 0.f};

    for (int idx = tid; idx < 64 * 128; idx += 256) {
        float d = d_e[idx >> 7];
        mst[idx] = macc_e[idx] * (d > 0.f ? 1.f / d : 0.f);
    }
    STAGE_W(Ws);
    if (w < 2) {
#pragma unroll
        for (int kt = 0; kt < 4; ++kt) {
            f16x8 v = cvt8(prot + (size_t)(w * 16 + ul) * 128 + kt * 32 + q * 8);
            *(f16x8*)&pfr[(size_t)((w * 4 + kt) * 64 + lane) * 8] = v;
        }
    }
    STAGE_ROWS16(esf, e_s);
    __syncthreads();
    {
        int c = tid & 127, rh = tid >> 7;
        for (int rb = 0; rb < 8; ++rb) {
            int r = rb * 2 + rh;
            const int* hrow = Hp + (size_t)(n0 + r) * 64;
            float acc = 0.f, dsum = 0.f;
            for (int j = 0; j < 64; ++j) {
                float s = (float)hrow[j];
                dsum += s;
                acc += s * mst[j * 128 + c];
            }
            float inv = dsum > 0.f ? 1.f / dsum : 0.f;
            float v = lrelu_(acc * inv + bp[c]);
            float er = esf[r][c] - v;
            erf[r][c] = er;
            ep_g[(size_t)(n0 + r) * 128 + c] = v;
            er_g[(size_t)(n0 + r) * 128 + c] = er;
        }
    }
    __syncthreads();
    {
        f16x8 af[4]; LOAD_AF(af, erf);
        f32x4 a0 = Z4, a1 = Z4;
        MM128T(af, a0, a1);
        float bv0 = bs[w * 32 + ul], bv1 = bs[w * 32 + 16 + ul];
#pragma unroll
        for (int j = 0; j < 4; ++j) {
            xwf[q * 4 + j][w * 32 + ul]      = a0[j] + bv0;
            xwf[q * 4 + j][w * 32 + 16 + ul] = a1[j] + bv1;
        }
        if (w < 2) {
            f32x4 ab = Z4;
#pragma unroll
            for (int kt = 0; kt < 4; ++kt) {
                f16x8 bb = *(const f16x8*)&pfr[(size_t)((w * 4 + kt) * 64 + lane) * 8];
                ab = __builtin_amdgcn_mfma_f32_16x16x32_f16(af[kt], bb, ab, 0, 0, 0);
            }
#pragma unroll
            for (int j = 0; j < 4; ++j) {
                float s = sigmoidf_(ab[j]);
                betaf[q * 4 + j][w * 16 + ul] = s;
                beta_g[(size_t)(n0 + q * 4 + j) * 32 + w * 16 + ul] = s;
            }
        }
    }
    __syncthreads();
    if (tid < 16) {
        float s = 0.f;
        for (int k = 0; k < 32; ++k) s += betaf[tid][k];
        dn_g[n0 + tid] = s > 0.f ? rsqrtf(s) : 0.f;
    }
    {
        int pair = tid >> 7, c = tid & 127;
        float acc[32];
#pragma unroll
        for (int i = 0; i < 32; ++i) acc[i] = 0.f;
        float dcnt = 0.f;
        for (int r = pair; r < 16; r += 2) {
            float sval = betaf[r][lane & 31];
            float xc = xwf[r][c];
            dcnt += sval;
            int sv = __float_as_int(sval);
#pragma unroll
            for (int jj = 0; jj < 32; ++jj)
                acc[jj] += __int_as_float(__builtin_amdgcn_readlane(sv, jj)) * xc;
        }
#pragma unroll
        for (int jj = 0; jj < 32; ++jj)
            atomicAdd(&macc_2[(size_t)jj * 128 + c], acc[jj]);
        if ((w & 1) == 0 && (lane & 32) == 0)
            atomicAdd(&d_e2[lane], dcnt);
    }
}

// ---- kE: e_h, e_res, e_al = lrelu(e_res@Wa+ba), final out ----
__global__ __launch_bounds__(256) void k_postE(
    const float* __restrict__ ep_g, const float* __restrict__ er_g,
    const float* __restrict__ beta_g, const float* __restrict__ dn_g,
    const float* __restrict__ macc_2, const float* __restrict__ d_e2,
    const float* __restrict__ Wa, const float* __restrict__ ba,
    const float* __restrict__ Wf, const float* __restrict__ bf,
    float* __restrict__ out)
{
    __shared__ __align__(16) _Float16 wfr[32 * 64 * 8];
    __shared__ float mst[32 * 128];
    __shared__ float erf[16][132], ehf[16][132], ealf[16][132];
    __shared__ float betaf[16][36];
    __shared__ float dnf[16];
    int tid = threadIdx.x;
    int w = tid >> 6, lane = tid & 63;
    int ul = lane & 15, q = lane >> 4;
    int n0 = blockIdx.x * 16;
    const f32x4 Z4 = {0.f, 0.f, 0.f, 0.f};

    for (int idx = tid; idx < 32 * 128; idx += 256) {
        float d = d_e2[idx >> 7];
        mst[idx] = macc_2[idx] * (d > 0.f ? 1.f / d : 0.f);
    }
    STAGE_W(Wa);
    STAGE_ROWS16(erf, er_g);
    for (int idx = tid; idx < 16 * 32; idx += 256)
        betaf[idx >> 5][idx & 31] = beta_g[(size_t)(n0 + (idx >> 5)) * 32 + (idx & 31)];
    if (tid < 16) dnf[tid] = dn_g[n0 + tid];
    __syncthreads();
    {
        int c = tid & 127, rh = tid >> 7;
        for (int rb = 0; rb < 8; ++rb) {
            int r = rb * 2 + rh;
            float acc = 0.f;
            for (int j = 0; j < 32; ++j)
                acc += betaf[r][j] * mst[j * 128 + c];
            float v = lrelu_(acc * dnf[r]);
            ehf[r][c] = v;
            erf[r][c] = erf[r][c] - v;           // e_res in place
        }
    }
    __syncthreads();
    {
        f16x8 af[4]; LOAD_AF(af, erf);
        f32x4 a0 = Z4, a1 = Z4;
        MM128T(af, a0, a1);
        float bv0 = ba[w * 32 + ul], bv1 = ba[w * 32 + 16 + ul];
#pragma unroll
        for (int j = 0; j < 4; ++j) {
            ealf[q * 4 + j][w * 32 + ul]      = lrelu_(a0[j] + bv0);
            ealf[q * 4 + j][w * 32 + 16 + ul] = lrelu_(a1[j] + bv1);
        }
    }
    __syncthreads();
    {
        int r = tid >> 4, i = tid & 15;
        float acc = 0.f;
#pragma unroll
        for (int kk = 0; kk < 8; ++kk) {
            int c = i * 8 + kk;
            acc += ep_g[(size_t)(n0 + r) * 128 + c] * Wf[c]
                 + ehf[r][c] * Wf[128 + c] + ealf[r][c] * Wf[256 + c];
        }
#pragma unroll
        for (int m = 1; m < 16; m <<= 1) acc += __shfl_xor(acc, m);
        if (i == 0) out[n0 + r] = acc + bf[0];
    }
}

extern "C" void kernel_launch(void* const* d_in, const int* in_sizes, int n_in,
                              void* d_out, int out_size, void* d_ws, size_t ws_size,
                              hipStream_t stream)
{
    const float* x     = (const float*)d_in[0];
    const int*   Hp    = (const int*)d_in[1];
    const float* ln_g  = (const float*)d_in[2];
    const float* ln_b  = (const float*)d_in[3];
    const float* W_ih0 = (const float*)d_in[4];
    const float* W_hh0 = (const float*)d_in[5];
    const float* b_ih0 = (const float*)d_in[6];
    const float* b_hh0 = (const float*)d_in[7];
    const float* W_ih1 = (const float*)d_in[8];
    const float* W_hh1 = (const float*)d_in[9];
    const float* b_ih1 = (const float*)d_in[10];
    const float* b_hh1 = (const float*)d_in[11];
    const float* Wp    = (const float*)d_in[12];
    const float* bp    = (const float*)d_in[13];
    const float* prot  = (const float*)d_in[14];
    const float* Ws    = (const float*)d_in[15];
    const float* bs    = (const float*)d_in[16];
    const float* Wa    = (const float*)d_in[17];
    const float* ba    = (const float*)d_in[18];
    const float* Wf    = (const float*)d_in[19];
    const float* bf    = (const float*)d_in[20];
    float* out = (float*)d_out;
    (void)n_in; (void)out_size; (void)ws_size;

    const int T = 64;
    int N = in_sizes[0] / (T * 128);         // 4000
    size_t NT = (size_t)N * T;
    int NB = N / 16;                          // 250

    char* ws = (char*)d_ws;
    size_t off = 0;
    auto alloc = [&](size_t bytes) { char* p = ws + off; off += (bytes + 255) & ~(size_t)255; return p; };
    _Float16* xn = (_Float16*)alloc(NT * 128 * 2);
    float* e_s   = (float*)alloc((size_t)N * 128 * 4);
    float* e_p   = (float*)alloc((size_t)N * 128 * 4);
    float* e_r   = (float*)alloc((size_t)N * 128 * 4);
    float* beta  = (float*)alloc((size_t)N * 32 * 4);
    float* dn    = (float*)alloc((size_t)N * 4);
    float* macc  = (float*)alloc((64 * 128 + 64 + 32 * 128 + 32) * 4);
    float* macc_e = macc;
    float* d_e    = macc + 64 * 128;
    float* macc_2 = d_e + 64;
    float* d_e2   = macc_2 + 32 * 128;

    k_ln<<<(int)(NT / 16), 256, 0, stream>>>(x, ln_g, ln_b, xn, N);
    k_gru2<<<NB, 512, 0, stream>>>(xn, W_ih0, W_hh0, b_ih0, b_hh0,
                                   W_ih1, W_hh1, b_ih1, b_hh1, e_s, N);

    hipMemsetAsync(macc, 0, (64 * 128 + 64 + 32 * 128 + 32) * 4, stream);

    k_postA<<<NB, 256, 0, stream>>>(e_s, Hp, Wp, macc_e, d_e);
    k_postC<<<NB, 256, 0, stream>>>(e_s, Hp, bp, prot, Ws, bs, macc_e, d_e,
                                    e_p, e_r, beta, dn, macc_2, d_e2);
    k_postE<<<NB, 256, 0, stream>>>(e_p, e_r, beta, dn, macc_2, d_e2,
                                    Wa, ba, Wf, bf, out);
}